// Round 16
// baseline (241.372 us; speedup 1.0000x reference)
//
#include <hip/hip_runtime.h>
#include <math.h>

// Problem constants
#define BB 2
#define TT 2048
#define DM 1024
#define NH 16
#define HD 64
#define FEAT 16
#define WIN 64
#define RTOT (BB*TT)        // 4096 rows

typedef __bf16 bf16x8 __attribute__((ext_vector_type(8)));
typedef float  f32x4  __attribute__((ext_vector_type(4)));

__device__ __forceinline__ unsigned short f2bf(float f) {
    union { float f; unsigned u; } v; v.f = f;
    unsigned r = v.u + 0x7FFFu + ((v.u >> 16) & 1u);   // RNE
    return (unsigned short)(r >> 16);
}
__device__ __forceinline__ float bf2f(unsigned short u) {
    union { unsigned u; float f; } v; v.u = ((unsigned)u) << 16; return v.f;
}

__device__ __forceinline__ void gl2lds16(const void* g, void* l) {
    __builtin_amdgcn_global_load_lds(
        (const __attribute__((address_space(1))) void*)g,
        (__attribute__((address_space(3))) void*)l, 16, 0, 0);
}

// ---------------------------------------------------------------------------
// Kernel 1 (merged): RMSNorm (blocks 0..4095) + weight transpose/bf16-cast.
// ---------------------------------------------------------------------------
__global__ __launch_bounds__(256) void prep_kernel(const float* __restrict__ x,
                                                   const float* __restrict__ w,
                                                   unsigned short* __restrict__ h_bf,
                                                   const float* __restrict__ W0,
                                                   const float* __restrict__ W1,
                                                   const float* __restrict__ W2,
                                                   const float* __restrict__ W3,
                                                   unsigned short* __restrict__ T0,
                                                   unsigned short* __restrict__ T1,
                                                   unsigned short* __restrict__ T2,
                                                   unsigned short* __restrict__ T3) {
    __shared__ float red[4];
    __shared__ float tile[64][65];
    int bx = blockIdx.x;
    int tid = threadIdx.x;
    if (bx < RTOT) {
        int row = bx;
        const float4* xr = (const float4*)(x + (size_t)row * DM);
        float4 xv = xr[tid];
        float ss = xv.x*xv.x + xv.y*xv.y + xv.z*xv.z + xv.w*xv.w;
        #pragma unroll
        for (int off = 32; off > 0; off >>= 1) ss += __shfl_down(ss, off, 64);
        if ((tid & 63) == 0) red[tid >> 6] = ss;
        __syncthreads();
        float tot = red[0] + red[1] + red[2] + red[3];
        float scale = rsqrtf(tot * (1.0f / DM) + 1e-6f);
        float4 wv = ((const float4*)w)[tid];
        ushort4 o;
        o.x = f2bf(xv.x * scale * wv.x);
        o.y = f2bf(xv.y * scale * wv.y);
        o.z = f2bf(xv.z * scale * wv.z);
        o.w = f2bf(xv.w * scale * wv.w);
        *(ushort4*)&h_bf[(size_t)row * DM + tid * 4] = o;
        return;
    }
    int t = bx - RTOT;
    int z = t >> 9;
    int rem = t & 511;
    int by = rem >> 4;
    int bxx = rem & 15;
    int K = (z == 3) ? 2048 : 1024;
    const int N = 1024;
    if (by * 64 >= K) return;
    const float* W = (z == 0) ? W0 : (z == 1) ? W1 : (z == 2) ? W2 : W3;
    unsigned short* WT = (z == 0) ? T0 : (z == 1) ? T1 : (z == 2) ? T2 : T3;
    int k0 = by * 64, n0 = bxx * 64;
    int r = tid >> 4, c4 = (tid & 15) * 4;
    #pragma unroll
    for (int i = 0; i < 4; i++) {
        float4 vv = *(const float4*)&W[(size_t)(k0 + r + i*16) * N + n0 + c4];
        tile[r + i*16][c4 + 0] = vv.x;
        tile[r + i*16][c4 + 1] = vv.y;
        tile[r + i*16][c4 + 2] = vv.z;
        tile[r + i*16][c4 + 3] = vv.w;
    }
    __syncthreads();
    int rn = tid >> 2, kq = (tid & 3) * 16;
    unsigned short u[16];
    #pragma unroll
    for (int i = 0; i < 16; i++) u[i] = f2bf(tile[kq + i][rn]);
    size_t base = (size_t)(n0 + rn) * K + k0 + kq;
    *(uint4*)&WT[base]     = *(uint4*)&u[0];
    *(uint4*)&WT[base + 8] = *(uint4*)&u[8];
}

// ---------------------------------------------------------------------------
// bf16 MFMA GEMM core: 128x128 tile, 4 waves, BK=64, 2-half schedule.
// R16: shrunk from 256x256/8-wave (128KB LDS, 1 block/CU, 192-block grid
// leaving 64 CUs idle) to 128x128/4-wave (64KB LDS -> 2 blocks/CU, 768/1024
// block grids covering all CUs; resident blocks overlap each other's
// barrier stalls). Staging/vmcnt bookkeeping is geometry-independent and
// carried over unchanged: per region 2 loads/thread; prologue 8 loads ->
// wait-4; each half stages 2 regions (+4) -> wait-4. K order and swizzle
// identical -> bit-identical numerics.
// ---------------------------------------------------------------------------
template<int LD, int NT>
__device__ __forceinline__ void gemm128_core(const unsigned short* __restrict__ A,
                                             const unsigned short* __restrict__ BT,
                                             unsigned short* __restrict__ Cb,
                                             int k0g) {
    const int N = 1024;
    // [buf][region: 0=A-ks0, 1=B-ks0, 2=A-ks1, 3=B-ks1][128*32]
    __shared__ __align__(16) unsigned short L[2][4][128 * 32];   // 64 KB
    int tid = threadIdx.x;            // 0..255
    int lane = tid & 63;
    int w = tid >> 6;                 // 0..3
    int wm = (w >> 1) * 64, wn = (w & 1) * 64;
    int m0 = blockIdx.y * 128, n0 = blockIdx.x * 128;
    int hi = lane >> 4;
    int l15 = lane & 15;

    // staging: each region = 512 16B slots; thread covers slots tid, tid+256
    int c0 = tid, c1 = tid + 256;
    int r0 = c0 >> 2, kh0 = ((c0 & 3) - (r0 >> 1)) & 3;
    int r1 = c1 >> 2, kh1 = ((c1 & 3) - (r1 >> 1)) & 3;
    const unsigned short* aS0 = A  + (size_t)(m0 + r0) * LD + k0g + kh0 * 8;
    const unsigned short* aS1 = A  + (size_t)(m0 + r1) * LD + k0g + kh1 * 8;
    const unsigned short* bS0 = BT + (size_t)(n0 + r0) * LD + k0g + kh0 * 8;
    const unsigned short* bS1 = BT + (size_t)(n0 + r1) * LD + k0g + kh1 * 8;

    int aoff[4], boff[4];
    #pragma unroll
    for (int i = 0; i < 4; i++) {
        int m = wm + i * 16 + l15;
        aoff[i] = m * 32 + (((hi + (m >> 1)) & 3) * 8);
    }
    #pragma unroll
    for (int j = 0; j < 4; j++) {
        int n = wn + j * 16 + l15;
        boff[j] = n * 32 + (((hi + (n >> 1)) & 3) * 8);
    }

    f32x4 acc[4][4];
    #pragma unroll
    for (int i = 0; i < 4; i++)
        #pragma unroll
        for (int j = 0; j < 4; j++)
            acc[i][j] = (f32x4){0.f, 0.f, 0.f, 0.f};

#define STG8(kt, bf, rg) do {                                         \
        int _go = (kt) * 64 + ((rg) >> 1) * 32;                       \
        unsigned short* _d = &L[bf][rg][0];                           \
        if ((rg) & 1) { gl2lds16(bS0 + _go, _d + c0 * 8);             \
                        gl2lds16(bS1 + _go, _d + c1 * 8); }           \
        else          { gl2lds16(aS0 + _go, _d + c0 * 8);             \
                        gl2lds16(aS1 + _go, _d + c1 * 8); }           \
    } while (0)

    STG8(0, 0, 0); STG8(0, 0, 1); STG8(0, 0, 2); STG8(0, 0, 3);
    asm volatile("s_waitcnt vmcnt(4)" ::: "memory");
    __builtin_amdgcn_s_barrier();

    for (int t = 0; t < NT; t++) {
        int rd = t & 1, st = rd ^ 1;
        bool stg = (t + 1 < NT);
        const unsigned short* A0 = &L[rd][0][0];
        const unsigned short* B0 = &L[rd][1][0];
        const unsigned short* A1 = &L[rd][2][0];
        const unsigned short* B1 = &L[rd][3][0];
        bf16x8 af[4], bfr[4];

        // ---- half A: k-slice 0 (regions 0,1), 16 MFMA ----
        asm volatile("" ::: "memory");
        #pragma unroll
        for (int i = 0; i < 4; i++) af[i] = *(const bf16x8*)&A0[aoff[i]];
        #pragma unroll
        for (int j = 0; j < 4; j++) bfr[j] = *(const bf16x8*)&B0[boff[j]];
        if (stg) { STG8(t + 1, st, 0); STG8(t + 1, st, 1); }
        __builtin_amdgcn_s_setprio(1);
        #pragma unroll
        for (int i = 0; i < 4; i++)
            #pragma unroll
            for (int j = 0; j < 4; j++)
                acc[i][j] = __builtin_amdgcn_mfma_f32_16x16x32_bf16(af[i], bfr[j], acc[i][j], 0, 0, 0);
        __builtin_amdgcn_s_setprio(0);
        if (stg) {
            asm volatile("s_waitcnt vmcnt(4)" ::: "memory");
        } else {
            asm volatile("s_waitcnt vmcnt(0)" ::: "memory");
        }
        __builtin_amdgcn_s_barrier();

        // ---- half B: k-slice 1 (regions 2,3), 16 MFMA ----
        asm volatile("" ::: "memory");
        #pragma unroll
        for (int i = 0; i < 4; i++) af[i] = *(const bf16x8*)&A1[aoff[i]];
        #pragma unroll
        for (int j = 0; j < 4; j++) bfr[j] = *(const bf16x8*)&B1[boff[j]];
        if (stg) { STG8(t + 1, st, 2); STG8(t + 1, st, 3); }
        __builtin_amdgcn_s_setprio(1);
        #pragma unroll
        for (int i = 0; i < 4; i++)
            #pragma unroll
            for (int j = 0; j < 4; j++)
                acc[i][j] = __builtin_amdgcn_mfma_f32_16x16x32_bf16(af[i], bfr[j], acc[i][j], 0, 0, 0);
        __builtin_amdgcn_s_setprio(0);
        if (stg) {
            asm volatile("s_waitcnt vmcnt(4)" ::: "memory");
            __builtin_amdgcn_s_barrier();
        }
    }
#undef STG8

    #pragma unroll
    for (int i = 0; i < 4; i++) {
        #pragma unroll
        for (int j = 0; j < 4; j++) {
            int col = n0 + wn + j * 16 + l15;
            #pragma unroll
            for (int r = 0; r < 4; r++) {
                int row = m0 + wm + i * 16 + hi * 4 + r;
                Cb[(size_t)row * N + col] = f2bf(acc[i][j][r]);
            }
        }
    }
}

__global__ __launch_bounds__(256, 2) void gemm_qkv_mfma(const unsigned short* __restrict__ A,
                                                        const unsigned short* __restrict__ BT0,
                                                        const unsigned short* __restrict__ BT1,
                                                        const unsigned short* __restrict__ BT2,
                                                        unsigned short* __restrict__ C0,
                                                        unsigned short* __restrict__ C1,
                                                        unsigned short* __restrict__ C2) {
    const unsigned short* BT = (blockIdx.z == 0) ? BT0 : (blockIdx.z == 1) ? BT1 : BT2;
    unsigned short* C = (blockIdx.z == 0) ? C0 : (blockIdx.z == 1) ? C1 : C2;
    gemm128_core<1024, 16>(A, BT, C, 0);
}

__global__ __launch_bounds__(256, 2) void gemm_out_mfma(const unsigned short* __restrict__ A,
                                                        const unsigned short* __restrict__ BT,
                                                        unsigned short* __restrict__ P0,
                                                        unsigned short* __restrict__ P1,
                                                        unsigned short* __restrict__ P2,
                                                        unsigned short* __restrict__ P3) {
    unsigned short* P = (blockIdx.z == 0) ? P0 : (blockIdx.z == 1) ? P1
                      : (blockIdx.z == 2) ? P2 : P3;
    gemm128_core<2048, 8>(A, BT, P, blockIdx.z * 512);
}

__global__ __launch_bounds__(256) void out_reduce_kernel(const float* __restrict__ x,
                                                         const unsigned short* __restrict__ P0,
                                                         const unsigned short* __restrict__ P1,
                                                         const unsigned short* __restrict__ P2,
                                                         const unsigned short* __restrict__ P3,
                                                         float* __restrict__ out) {
    int g = blockIdx.x * 256 + threadIdx.x;
    size_t e = (size_t)g * 4;
    float4 xv = *(const float4*)&x[e];
    ushort4 a = *(const ushort4*)&P0[e];
    ushort4 b = *(const ushort4*)&P1[e];
    ushort4 c = *(const ushort4*)&P2[e];
    ushort4 d = *(const ushort4*)&P3[e];
    float4 o;
    o.x = xv.x + bf2f(a.x) + bf2f(b.x) + bf2f(c.x) + bf2f(d.x);
    o.y = xv.y + bf2f(a.y) + bf2f(b.y) + bf2f(c.y) + bf2f(d.y);
    o.z = xv.z + bf2f(a.z) + bf2f(b.z) + bf2f(c.z) + bf2f(d.z);
    o.w = xv.w + bf2f(a.w) + bf2f(b.w) + bf2f(c.w) + bf2f(d.w);
    *(float4*)&out[e] = o;
}

// ---------------------------------------------------------------------------
// Linear attention constants
// ---------------------------------------------------------------------------
#define PHI 160
#define NCH 32
#define KVROWS 65
#define CH_STRIDE ((size_t)32 * KVROWS * PHI)
#define KSTR 72   // staged raw K/Q row stride (conflict-free)
#define FSTR 18   // kf_l/qf_l row stride: 36B = 9 dwords -> 2 lanes/bank (free)

// ---------------------------------------------------------------------------
// FUSED: sliding-window attention (blockIdx.x < 32) + lin_kv (>= 32).
// (identical to R14/R15-passing version)
// ---------------------------------------------------------------------------
__global__ __launch_bounds__(256) void win_linkv_kernel(const unsigned short* __restrict__ q_bf,
                                                        const unsigned short* __restrict__ k_bf,
                                                        const float* __restrict__ Wkf,
                                                        const unsigned short* __restrict__ v_bf,
                                                        unsigned short* __restrict__ cat_bf,
                                                        unsigned short* __restrict__ kvbuf) {
    __shared__ __align__(16) unsigned short POOL[21136];   // 42.3 KB
    __shared__ float sclut[136];
    int bh = blockIdx.y;
    int h = bh & 15;
    int b = bh >> 4;
    int tid = threadIdx.x;
    int lane = tid & 63;

    if (blockIdx.x < TT / 64) {
        // =================== WIN path ===================
        unsigned short* Qs = POOL;
        unsigned short* Ks = POOL + 4096;
        unsigned short* Vt = POOL + 12288;
        unsigned short* Pl = POOL;
        int qtile = blockIdx.x;
        int wv = tid >> 6;
        int qr0 = wv * 16;
        int t0 = qtile * 64;
        int k0 = t0 - 64;

        #pragma unroll
        for (int half = 0; half < 2; half++) {
            int slot = tid + half * 256;
            int row = slot >> 3, pos = slot & 7;
            int o = (pos - row) & 7;
            gl2lds16(q_bf + (size_t)(b * TT + t0 + row) * (NH * HD) + h * HD + o * 8,
                     &Qs[slot * 8]);
        }
        #pragma unroll
        for (int qd = 0; qd < 4; qd++) {
            int slot = tid + qd * 256;
            int row = slot >> 3, pos = slot & 7;
            int o = (pos - row) & 7;
            int kg = k0 + row;
            if (kg >= 0) {
                gl2lds16(k_bf + (size_t)(b * TT + kg) * (NH * HD) + h * HD + o * 8,
                         &Ks[slot * 8]);
            } else {
                uint4 z = {0, 0, 0, 0};
                *(uint4*)&Ks[slot * 8] = z;
            }
        }
        {
            int kk = tid & 127;
            int dh = tid >> 7;
            int kg = k0 + kk;
            unsigned short tmp[32];
            if (kg >= 0) {
                size_t base = (size_t)(b * TT + kg) * (NH * HD) + h * HD + dh * 32;
                *(uint4*)&tmp[0]  = *(const uint4*)&v_bf[base];
                *(uint4*)&tmp[8]  = *(const uint4*)&v_bf[base + 8];
                *(uint4*)&tmp[16] = *(const uint4*)&v_bf[base + 16];
                *(uint4*)&tmp[24] = *(const uint4*)&v_bf[base + 24];
            } else {
                #pragma unroll
                for (int d = 0; d < 32; d++) tmp[d] = 0;
            }
            int o = kk >> 3, klow = kk & 7;
            #pragma unroll
            for (int d = 0; d < 32; d++) {
                int dim = dh * 32 + d;
                Vt[dim * 128 + ((o + dim) & 15) * 8 + klow] = tmp[d];
            }
        }
        __syncthreads();

        int hi = lane >> 4;
        int lan15 = lane & 15;
        f32x4 sc[8];
        #pragma unroll
        for (int nt = 0; nt < 8; nt++) sc[nt] = (f32x4){0.f, 0.f, 0.f, 0.f};
        #pragma unroll
        for (int ks = 0; ks < 2; ks++) {
            int m = qr0 + lan15;
            int oA = ks * 4 + hi;
            bf16x8 a = *(const bf16x8*)&Qs[m * 64 + ((oA + m) & 7) * 8];
            #pragma unroll
            for (int nt = 0; nt < 8; nt++) {
                int n = nt * 16 + lan15;
                bf16x8 bb = *(const bf16x8*)&Ks[n * 64 + ((oA + n) & 7) * 8];
                sc[nt] = __builtin_amdgcn_mfma_f32_16x16x32_bf16(a, bb, sc[nt], 0, 0, 0);
            }
        }

        float lrow[4];
        #pragma unroll
        for (int r = 0; r < 4; r++) {
            int tq = t0 + qr0 + hi * 4 + r;
            float mx = -1e30f;
            #pragma unroll
            for (int nt = 0; nt < 8; nt++) {
                int s = k0 + nt * 16 + lan15;
                bool ok = (s >= 0) && (s <= tq) && (s >= tq - WIN);
                float vv = ok ? sc[nt][r] * 0.125f : -1e30f;
                sc[nt][r] = vv;
                mx = fmaxf(mx, vv);
            }
            #pragma unroll
            for (int off = 1; off < 16; off <<= 1) mx = fmaxf(mx, __shfl_xor(mx, off, 64));
            float ls = 0.f;
            #pragma unroll
            for (int nt = 0; nt < 8; nt++) {
                float e = __expf(sc[nt][r] - mx);
                sc[nt][r] = e;
                ls += e;
            }
            #pragma unroll
            for (int off = 1; off < 16; off <<= 1) ls += __shfl_xor(ls, off, 64);
            lrow[r] = ls;
        }

        __syncthreads();   // Qs/Ks reads complete in ALL waves before Pl overwrite

        #pragma unroll
        for (int nt = 0; nt < 8; nt++) {
            #pragma unroll
            for (int r = 0; r < 4; r++) {
                int row = qr0 + hi * 4 + r;
                int col = nt * 16 + lan15;
                Pl[row * 128 + (((col >> 3) + row) & 15) * 8 + (col & 7)] = f2bf(sc[nt][r]);
            }
        }
        __syncthreads();

        f32x4 y[4];
        #pragma unroll
        for (int nt = 0; nt < 4; nt++) y[nt] = (f32x4){0.f, 0.f, 0.f, 0.f};
        #pragma unroll
        for (int ks = 0; ks < 4; ks++) {
            int m = qr0 + lan15;
            int oA = ks * 4 + hi;
            bf16x8 a = *(const bf16x8*)&Pl[m * 128 + ((oA + m) & 15) * 8];
            #pragma unroll
            for (int nt = 0; nt < 4; nt++) {
                int n = nt * 16 + lan15;
                bf16x8 bb = *(const bf16x8*)&Vt[n * 128 + ((oA + n) & 15) * 8];
                y[nt] = __builtin_amdgcn_mfma_f32_16x16x32_bf16(a, bb, y[nt], 0, 0, 0);
            }
        }

        #pragma unroll
        for (int nt = 0; nt < 4; nt++) {
            #pragma unroll
            for (int r = 0; r < 4; r++) {
                int row = qr0 + hi * 4 + r;
                int dim = nt * 16 + lan15;
                cat_bf[(size_t)(b * TT + t0 + row) * (2 * DM) + DM + h * HD + dim] =
                    f2bf(y[nt][r] / lrow[r]);
            }
        }
        return;
    }

    // =================== LIN_KV path ===================
    {
        unsigned short* kf_l = POOL;                 // 64 x FSTR
        unsigned short* PhiT = POOL + 1152;
        unsigned short* Vt   = POOL + 15744;
        unsigned short* iu   = POOL + 20864;
        unsigned short* ju   = POOL + 21000;
        int c = blockIdx.x - TT / 64;
        int w = tid >> 6;
        int hi = lane >> 4, l15 = lane & 15;

        unsigned short* ks_l = &PhiT[0];            // 64xKSTR staged K rows
        float* Wf = (float*)&PhiT[64 * KSTR];       // 64x16 f32 weights

        if (tid < 136) {
            int qq = tid, i = 0;
            while (qq >= 16 - i) { qq -= 16 - i; i++; }
            iu[tid] = (unsigned short)i; ju[tid] = (unsigned short)(i + qq);
            sclut[tid] = (qq == 0) ? 0.5f : 0.70710678118654752f;
        }
        {
            int r = tid >> 2, q16 = (tid & 3) * 16;
            size_t gb = ((size_t)(b * TT + c * 64 + r)) * DM + h * HD + q16;
            *(uint4*)&ks_l[r * KSTR + q16]     = *(const uint4*)&k_bf[gb];
            *(uint4*)&ks_l[r * KSTR + q16 + 8] = *(const uint4*)&k_bf[gb + 8];
        }
        ((float4*)Wf)[tid] = ((const float4*)Wkf)[tid];
        {
            int p = tid & 31, dq = (tid >> 5) * 8;
            size_t base0 = ((size_t)(b * TT + c * 64 + 2 * p)) * DM + h * HD + dq;
            unsigned short a[8], bq[8];
            *(uint4*)a  = *(const uint4*)&v_bf[base0];
            *(uint4*)bq = *(const uint4*)&v_bf[base0 + DM];
            int colo = p >> 2, coll = (2 * p) & 7;
            #pragma unroll
            for (int d = 0; d < 8; d++) {
                int row = dq + d;
                ushort2 u; u.x = a[d]; u.y = bq[d];
                *(ushort2*)&Vt[row * 64 + ((colo + row) & 7) * 8 + coll] = u;
            }
            #pragma unroll
            for (int i = 0; i < 4; i++) {
                int e = tid + i * 256;
                Vt[(64 + (e >> 6)) * 64 + (e & 63)] = 0x3F80;
            }
        }
        __syncthreads();
        {
            int r = tid >> 2, f0 = (tid & 3) * 4;
            const unsigned short* kr = &ks_l[r * KSTR];
            float a0 = 0.f, a1 = 0.f, a2 = 0.f, a3 = 0.f;
            #pragma unroll 8
            for (int d = 0; d < HD; d++) {
                float kv = bf2f(kr[d]);
                const float* wr = &Wf[d * FEAT + f0];
                a0 += kv * wr[0]; a1 += kv * wr[1]; a2 += kv * wr[2]; a3 += kv * wr[3];
            }
            ushort2 o01; o01.x = f2bf(a0); o01.y = f2bf(a1);
            ushort2 o23; o23.x = f2bf(a2); o23.y = f2bf(a3);
            *(ushort2*)&kf_l[r * FSTR + f0]     = o01;
            *(ushort2*)&kf_l[r * FSTR + f0 + 2] = o23;
        }
        __syncthreads();
        {
            int s = tid & 63, fb = tid >> 6;
            const unsigned short* krow = &kf_l[s * FSTR];
            for (int it = 0; it < 40; it++) {
                int f = fb * 40 + it;
                float val;
                if (f == 0) val = 1.f;
                else if (f < 17) val = bf2f(krow[f - 1]);
                else if (f < 153) { int qq = f - 17; val = bf2f(krow[iu[qq]]) * bf2f(krow[ju[qq]]) * sclut[qq]; }
                else val = 0.f;   // f in [153,160): zero padding (guard load-bearing!)
                PhiT[f * 76 + s] = f2bf(val);
            }
        }
        __syncthreads();
        f32x4 acc[5][3];
        #pragma unroll
        for (int m = 0; m < 5; m++)
            #pragma unroll
            for (int j = 0; j < 3; j++) acc[m][j] = (f32x4){0.f, 0.f, 0.f, 0.f};
        #pragma unroll
        for (int ks = 0; ks < 2; ks++) {
            bf16x8 bfrag[3];
            #pragma unroll
            for (int j = 0; j < 3; j++)
                bfrag[j] = *(const bf16x8*)&PhiT[((3 * w + j) * 16 + l15) * 76 + ks * 32 + hi * 8];
            #pragma unroll
            for (int m = 0; m < 5; m++) {
                int mrow = m * 16 + l15;
                bf16x8 afrag = *(const bf16x8*)&Vt[mrow * 64 + (((ks * 4 + hi) + mrow) & 7) * 8];
                #pragma unroll
                for (int j = 0; j < 3; j++)
                    acc[m][j] = __builtin_amdgcn_mfma_f32_16x16x32_bf16(afrag, bfrag[j], acc[m][j], 0, 0, 0);
            }
        }
        size_t obase = ((size_t)c * 32 + bh) * (KVROWS * PHI);
        #pragma unroll
        for (int m = 0; m < 5; m++) {
            #pragma unroll
            for (int j = 0; j < 3; j++) {
                int f = (3 * w + j) * 16 + l15;
                if (f >= PHI) continue;
                #pragma unroll
                for (int r = 0; r < 4; r++) {
                    int row = m * 16 + hi * 4 + r;
                    if (row >= KVROWS) continue;
                    kvbuf[obase + row * PHI + f] = f2bf(acc[m][j][r]);
                }
            }
        }
    }
}

// Phase C: in-place exclusive prefix over chunks. grid (41, 32 bh)
__global__ __launch_bounds__(256) void lin_scan_kernel(unsigned short* __restrict__ kvbuf) {
    int e = blockIdx.x * 256 + threadIdx.x;
    int bh = blockIdx.y;
    if (e >= KVROWS * PHI) return;
    float acc = 0.f;
    size_t off = (size_t)bh * (KVROWS * PHI) + e;
    for (int c = 0; c < NCH; c++) {
        float vv = bf2f(kvbuf[off]);
        kvbuf[off] = f2bf(acc);
        acc += vv;
        off += CH_STRIDE;
    }
}

// ---------------------------------------------------------------------------
// Phase D: outputs. grid (32 chunks, 32 bh), 512 threads (8 waves).
// (identical to R15-passing version)
// ---------------------------------------------------------------------------
__global__ __launch_bounds__(512) void lin_out_kernel(const unsigned short* __restrict__ q_bf,
                                                      const unsigned short* __restrict__ k_bf,
                                                      const float* __restrict__ Wqf,
                                                      const float* __restrict__ Wkf,
                                                      const unsigned short* __restrict__ v_bf,
                                                      const unsigned short* __restrict__ kvbuf,
                                                      unsigned short* __restrict__ cat_bf) {
    int c = blockIdx.x, bh = blockIdx.y;
    int h = bh & 15, b = bh >> 4;
    int tid = threadIdx.x, lane = tid & 63, w = tid >> 6;
    int hi = lane >> 4, l15 = lane & 15;
    int g = w >> 2;                 // wave-group 0/1

    __shared__ unsigned short qf_l[64 * FSTR];
    __shared__ __align__(16) unsigned short kf_lb[64 * 34];   // cols 16..31 zero
    __shared__ __align__(16) unsigned short KVS_l[80 * 164];  // rows 65..79 zero
    __shared__ __align__(16) unsigned short Vt[80 * 64];      // swizzled + ones rows
    __shared__ __align__(16) unsigned short Phi_l[64 * 164];  // [token][f]
    __shared__ __align__(16) unsigned short P_l[64 * 64];     // swizzled
    __shared__ unsigned short iu[136], ju[136];
    __shared__ float sclut[136];
    float* zbuf = sclut;            // aliased: sclut dead after Phi build

    unsigned short* qs_l = &KVS_l[0];              // 64xKSTR staged Q rows
    unsigned short* ks_l = &KVS_l[64 * KSTR];      // 64xKSTR staged K rows
    float* Wq_s = (float*)&Phi_l[0];               // 4KB
    float* Wk_s = (float*)&Phi_l[2048];            // 4KB

    if (tid < 136) {
        int qq = tid, i = 0;
        while (qq >= 16 - i) { qq -= 16 - i; i++; }
        iu[tid] = (unsigned short)i; ju[tid] = (unsigned short)(i + qq);
        sclut[tid] = (qq == 0) ? 0.5f : 0.70710678118654752f;
    }
    {   // stage Q (tid<256) and K (tid>=256) rows coalesced (stride KSTR)
        int t2 = tid & 255;
        int r = t2 >> 2, q16 = (t2 & 3) * 16;
        size_t gq = ((size_t)(b * TT + c * 64 + r)) * DM + h * HD + q16;
        if (tid < 256) {
            *(uint4*)&qs_l[r * KSTR + q16]     = *(const uint4*)&q_bf[gq];
            *(uint4*)&qs_l[r * KSTR + q16 + 8] = *(const uint4*)&q_bf[gq + 8];
        } else {
            *(uint4*)&ks_l[r * KSTR + q16]     = *(const uint4*)&k_bf[gq];
            *(uint4*)&ks_l[r * KSTR + q16 + 8] = *(const uint4*)&k_bf[gq + 8];
        }
    }
    if (tid < 256) ((float4*)Wq_s)[tid] = ((const float4*)Wqf)[tid];
    else           ((float4*)Wk_s)[tid - 256] = ((const float4*)Wkf)[tid - 256];
    if (tid < 256) {   // stage V^T swizzled + ones rows (256-thread form)
        int p = tid & 31, dq = (tid >> 5) * 8;
        size_t base0 = ((size_t)(b * TT + c * 64 + 2 * p)) * DM + h * HD + dq;
        unsigned short a[8], bq[8];
        *(uint4*)a  = *(const uint4*)&v_bf[base0];
        *(uint4*)bq = *(const uint4*)&v_bf[base0 + DM];
        int colo = p >> 2, coll = (2 * p) & 7;
        #pragma unroll
        for (int d = 0; d < 8; d++) {
            int row = dq + d;
            ushort2 u; u.x = a[d]; u.y = bq[d];
            *(ushort2*)&Vt[row * 64 + ((colo + row) & 7) * 8 + coll] = u;
        }
        #pragma unroll
        for (int i = 0; i < 4; i++) {
            int e = tid + i * 256;
            Vt[(64 + (e >> 6)) * 64 + (e & 63)] = 0x3F80;
        }
    }
    __syncthreads();
    {   // compute qf_l and kf_lb: 8 threads/row, 2 features each (fp32, d asc)
        int r = tid >> 3, f0 = (tid & 7) * 2;
        const unsigned short* qr = &qs_l[r * KSTR];
        const unsigned short* kr = &ks_l[r * KSTR];
        float qa0 = 0.f, qa1 = 0.f, ka0 = 0.f, ka1 = 0.f;
        #pragma unroll 8
        for (int d = 0; d < HD; d++) {
            float qv = bf2f(qr[d]);
            float kv = bf2f(kr[d]);
            const float* wq = &Wq_s[d * FEAT + f0];
            const float* wk = &Wk_s[d * FEAT + f0];
            qa0 += qv * wq[0]; qa1 += qv * wq[1];
            ka0 += kv * wk[0]; ka1 += kv * wk[1];
        }
        ushort2 q01; q01.x = f2bf(qa0); q01.y = f2bf(qa1);
        ushort2 k01; k01.x = f2bf(ka0); k01.y = f2bf(ka1);
        *(ushort2*)&qf_l[r * FSTR + f0] = q01;
        *(ushort2*)&kf_lb[r * 34 + f0] = k01;
        ushort2 z2 = {0, 0};
        *(ushort2*)&kf_lb[r * 34 + 16 + f0] = z2;
    }
    __syncthreads();
    {   // stage KVS rows 0..64 (overwrites qs/ks scratch - post-sync)
        size_t gbase = ((size_t)c * 32 + bh) * (KVROWS * PHI);
        #pragma unroll
        for (int i = 0; i < 6; i++) {
            int e4 = tid + i * 512;
            if (e4 < KVROWS * 40) {
                int r = e4 / 40, q4 = (e4 % 40) * 4;
                *(ushort4*)&KVS_l[r * 164 + q4] =
                    *(const ushort4*)&kvbuf[gbase + r * PHI + q4];
            }
        }
        #pragma unroll
        for (int i = 0; i < 2; i++) {
            int e4 = tid + i * 512;
            if (e4 < 15 * 40) {
                int r = 65 + e4 / 40, q4 = (e4 % 40) * 4;
                ushort4 z4 = {0, 0, 0, 0};
                *(ushort4*)&KVS_l[r * 164 + q4] = z4;
            }
        }
    }
    {   // build Phi_l[token][f]: 8 fb-groups x 20 iters (overwrites Wq/Wk)
        int s = tid & 63, fb = tid >> 6;
        const unsigned short* qrow = &qf_l[s * FSTR];
        for (int it = 0; it < 20; it++) {
            int f = fb * 20 + it;
            float val;
            if (f == 0) val = 1.f;
            else if (f < 17) val = bf2f(qrow[f - 1]);
            else if (f < 153) { int qq = f - 17; val = bf2f(qrow[iu[qq]]) * bf2f(qrow[ju[qq]]) * sclut[qq]; }
            else val = 0.f;   // f in [153,160): zero padding (guard load-bearing!)
            Phi_l[s * 164 + f] = f2bf(val);
        }
    }
    __syncthreads();

    int nlo = g * 3;                // g0: n=0..2, g1: n=3..4
    int ncnt = g ? 2 : 3;
    f32x4 acc[3];
    #pragma unroll
    for (int j = 0; j < 3; j++) acc[j] = (f32x4){0.f, 0.f, 0.f, 0.f};

    int t_m = (w & 3) * 16 + l15;

    // GEMM1: Phi (LDS) x KVS - n-split across wave groups
    #pragma unroll
    for (int ks = 0; ks < 5; ks++) {
        bf16x8 af = *(const bf16x8*)&Phi_l[t_m * 164 + ks * 32 + hi * 8];
        for (int jn = 0; jn < ncnt; jn++) {
            int n = nlo + jn;
            bf16x8 bb = *(const bf16x8*)&KVS_l[(n * 16 + l15) * 164 + ks * 32 + hi * 8];
            acc[jn] = __builtin_amdgcn_mfma_f32_16x16x32_bf16(af, bb, acc[jn], 0, 0, 0);
        }
    }

    // intra-chunk scores: sl-tile split (g0: n=0,1; g1: n=2,3)
    {
        union { unsigned short u[8]; bf16x8 v; } aq;
        #pragma unroll
        for (int j = 0; j < 8; j++) {
            int f = hi * 8 + j;
            aq.u[j] = (f < 16) ? qf_l[t_m * FSTR + f] : (unsigned short)0;
        }
        #pragma unroll
        for (int jn = 0; jn < 2; jn++) {
            int n = g * 2 + jn;
            bf16x8 bk = *(const bf16x8*)&kf_lb[(n * 16 + l15) * 34 + hi * 8];
            f32x4 zv = {0.f, 0.f, 0.f, 0.f};
            f32x4 sc = __builtin_amdgcn_mfma_f32_16x16x32_bf16(aq.v, bk, zv, 0, 0, 0);
            int sl = n * 16 + l15;
            #pragma unroll
            for (int r = 0; r < 4; r++) {
                int rl = (w & 3) * 16 + hi * 4 + r;
                float sv = 1.f + 0.5f * sc[r];
                sv = sv * sv;
                if (sl > rl) sv = 0.f;
                P_l[rl * 64 + (((sl >> 3) + rl) & 7) * 8 + (sl & 7)] = f2bf(sv);
            }
        }
    }
    __syncthreads();

    // GEMM2: P x Vt - same n-ownership as GEMM1
    #pragma unroll
    for (int ks = 0; ks < 2; ks++) {
        int oA = ks * 4 + hi;
        bf16x8 a = *(const bf16x8*)&P_l[t_m * 64 + ((oA + t_m) & 7) * 8];
        for (int jn = 0; jn < ncnt; jn++) {
            int n = nlo + jn;
            int nrow = n * 16 + l15;
            bf16x8 bb = *(const bf16x8*)&Vt[nrow * 64 + ((oA + nrow) & 7) * 8];
            acc[jn] = __builtin_amdgcn_mfma_f32_16x16x32_bf16(a, bb, acc[jn], 0, 0, 0);
        }
    }

    // z exchange: g1 owns n=4 (acc[1]); broadcast per row then publish to zbuf
    if (g == 1) {
        #pragma unroll
        for (int r = 0; r < 4; r++) {
            float zz = __shfl(acc[1][r], (lane & 48), 64);
            if (l15 == 0) zbuf[(w & 3) * 16 + hi * 4 + r] = zz;
        }
    }
    __syncthreads();

    // epilogue: y cols n<4 divided by z
    for (int jn = 0; jn < ncnt; jn++) {
        int n = nlo + jn;
        if (n >= 4) continue;
        #pragma unroll
        for (int r = 0; r < 4; r++) {
            int rowl = (w & 3) * 16 + hi * 4 + r;
            float zz = zbuf[rowl];
            int token = c * 64 + rowl;
            int d = n * 16 + l15;
            cat_bf[((size_t)(b * TT + token)) * (2 * DM) + h * HD + d] =
                f2bf(acc[jn][r] / (zz + 1e-6f));
        }
    }
}

// ---------------------------------------------------------------------------
extern "C" void kernel_launch(void* const* d_in, const int* in_sizes, int n_in,
                              void* d_out, int out_size, void* d_ws, size_t ws_size,
                              hipStream_t stream) {
    const float* x      = (const float*)d_in[0];
    const float* norm_w = (const float*)d_in[1];
    const float* Wq     = (const float*)d_in[2];
    const float* Wk     = (const float*)d_in[3];
    const float* Wv     = (const float*)d_in[4];
    const float* Wqf    = (const float*)d_in[5];
    const float* Wkf    = (const float*)d_in[6];
    const float* Wout   = (const float*)d_in[7];
    float* out = (float*)d_out;

    char* p = (char*)d_ws;
    unsigned short* h_bf = (unsigned short*)p; p += (size_t)RTOT * DM * 2;       // 8 MB
    unsigned short* WqT  = (unsigned short*)p; p += (size_t)DM * DM * 2;         // 2 MB
    unsigned short* WkT  = (unsigned short*)p; p += (size_t)DM * DM * 2;
    unsigned short* WvT  = (unsigned short*)p; p += (size_t)DM * DM * 2;
    unsigned short* WoT  = (unsigned short*)p; p += (size_t)DM * 2 * DM * 2;     // 4 MB
    unsigned short* q_bf = (unsigned short*)p; p += (size_t)RTOT * DM * 2;       // 8 MB
    unsigned short* k_bf = (unsigned short*)p; p += (size_t)RTOT * DM * 2;
    unsigned short* v_bf = (unsigned short*)p; p += (size_t)RTOT * DM * 2;
    p += (size_t)RTOT * NH * FEAT * 2 * 2;   // (former qf/kf buffers - unused)
    unsigned short* cat_bf = (unsigned short*)p; p += (size_t)RTOT * 2 * DM * 2;   // 16 MB
    unsigned short* kvbuf  = (unsigned short*)p; p += (size_t)NCH * 32 * KVROWS * PHI * 2; // 21.3 MB
    unsigned short* P0 = (unsigned short*)p; p += (size_t)RTOT * DM * 2;           // 8 MB
    unsigned short* P1 = (unsigned short*)p; p += (size_t)RTOT * DM * 2;           // 8 MB
    unsigned short* P2 = h_bf;
    unsigned short* P3 = q_bf;

    prep_kernel<<<RTOT + 2048, 256, 0, stream>>>(x, norm_w, h_bf,
                                                 Wq, Wk, Wv, Wout, WqT, WkT, WvT, WoT);
    gemm_qkv_mfma<<<dim3(8, 32, 3), 256, 0, stream>>>(h_bf, WqT, WkT, WvT, q_bf, k_bf, v_bf);
    win_linkv_kernel<<<dim3(2 * (TT / 64), BB * NH), 256, 0, stream>>>(q_bf, k_bf, Wkf, v_bf, cat_bf, kvbuf);
    lin_scan_kernel<<<dim3((KVROWS * PHI + 255) / 256, BB * NH), 256, 0, stream>>>(kvbuf);
    lin_out_kernel<<<dim3(NCH, BB * NH), 512, 0, stream>>>(q_bf, k_bf, Wqf, Wkf, v_bf, kvbuf, cat_bf);
    gemm_out_mfma<<<dim3(8, 32, 4), 256, 0, stream>>>(cat_bf, WoT, P0, P1, P2, P3);
    out_reduce_kernel<<<RTOT * DM / 1024, 256, 0, stream>>>(x, P0, P1, P2, P3, out);
}

// Round 17
// 234.783 us; speedup vs baseline: 1.0281x; 1.0281x over previous
//
#include <hip/hip_runtime.h>
#include <math.h>

// Problem constants
#define BB 2
#define TT 2048
#define DM 1024
#define NH 16
#define HD 64
#define FEAT 16
#define WIN 64
#define RTOT (BB*TT)        // 4096 rows

typedef __bf16 bf16x8 __attribute__((ext_vector_type(8)));
typedef float  f32x4  __attribute__((ext_vector_type(4)));

__device__ __forceinline__ unsigned short f2bf(float f) {
    union { float f; unsigned u; } v; v.f = f;
    unsigned r = v.u + 0x7FFFu + ((v.u >> 16) & 1u);   // RNE
    return (unsigned short)(r >> 16);
}
__device__ __forceinline__ float bf2f(unsigned short u) {
    union { unsigned u; float f; } v; v.u = ((unsigned)u) << 16; return v.f;
}

__device__ __forceinline__ void gl2lds16(const void* g, void* l) {
    __builtin_amdgcn_global_load_lds(
        (const __attribute__((address_space(1))) void*)g,
        (__attribute__((address_space(3))) void*)l, 16, 0, 0);
}

// ---------------------------------------------------------------------------
// Kernel 1 (merged): RMSNorm (blocks 0..4095) + weight transpose/bf16-cast.
// ---------------------------------------------------------------------------
__global__ __launch_bounds__(256) void prep_kernel(const float* __restrict__ x,
                                                   const float* __restrict__ w,
                                                   unsigned short* __restrict__ h_bf,
                                                   const float* __restrict__ W0,
                                                   const float* __restrict__ W1,
                                                   const float* __restrict__ W2,
                                                   const float* __restrict__ W3,
                                                   unsigned short* __restrict__ T0,
                                                   unsigned short* __restrict__ T1,
                                                   unsigned short* __restrict__ T2,
                                                   unsigned short* __restrict__ T3) {
    __shared__ float red[4];
    __shared__ float tile[64][65];
    int bx = blockIdx.x;
    int tid = threadIdx.x;
    if (bx < RTOT) {
        int row = bx;
        const float4* xr = (const float4*)(x + (size_t)row * DM);
        float4 xv = xr[tid];
        float ss = xv.x*xv.x + xv.y*xv.y + xv.z*xv.z + xv.w*xv.w;
        #pragma unroll
        for (int off = 32; off > 0; off >>= 1) ss += __shfl_down(ss, off, 64);
        if ((tid & 63) == 0) red[tid >> 6] = ss;
        __syncthreads();
        float tot = red[0] + red[1] + red[2] + red[3];
        float scale = rsqrtf(tot * (1.0f / DM) + 1e-6f);
        float4 wv = ((const float4*)w)[tid];
        ushort4 o;
        o.x = f2bf(xv.x * scale * wv.x);
        o.y = f2bf(xv.y * scale * wv.y);
        o.z = f2bf(xv.z * scale * wv.z);
        o.w = f2bf(xv.w * scale * wv.w);
        *(ushort4*)&h_bf[(size_t)row * DM + tid * 4] = o;
        return;
    }
    int t = bx - RTOT;
    int z = t >> 9;
    int rem = t & 511;
    int by = rem >> 4;
    int bxx = rem & 15;
    int K = (z == 3) ? 2048 : 1024;
    const int N = 1024;
    if (by * 64 >= K) return;
    const float* W = (z == 0) ? W0 : (z == 1) ? W1 : (z == 2) ? W2 : W3;
    unsigned short* WT = (z == 0) ? T0 : (z == 1) ? T1 : (z == 2) ? T2 : T3;
    int k0 = by * 64, n0 = bxx * 64;
    int r = tid >> 4, c4 = (tid & 15) * 4;
    #pragma unroll
    for (int i = 0; i < 4; i++) {
        float4 vv = *(const float4*)&W[(size_t)(k0 + r + i*16) * N + n0 + c4];
        tile[r + i*16][c4 + 0] = vv.x;
        tile[r + i*16][c4 + 1] = vv.y;
        tile[r + i*16][c4 + 2] = vv.z;
        tile[r + i*16][c4 + 3] = vv.w;
    }
    __syncthreads();
    int rn = tid >> 2, kq = (tid & 3) * 16;
    unsigned short u[16];
    #pragma unroll
    for (int i = 0; i < 16; i++) u[i] = f2bf(tile[kq + i][rn]);
    size_t base = (size_t)(n0 + rn) * K + k0 + kq;
    *(uint4*)&WT[base]     = *(uint4*)&u[0];
    *(uint4*)&WT[base + 8] = *(uint4*)&u[8];
}

// ---------------------------------------------------------------------------
// bf16 MFMA GEMM core: 256x256 tile, 8 waves, BK=64, 2-half schedule.
// (R14-measured-best configuration; R16's 128-tile shrink regressed +11us
// from doubled staging traffic per FLOP and halved MFMA per barrier.)
// ---------------------------------------------------------------------------
template<int LD, int NT>
__device__ __forceinline__ void gemm2h_core(const unsigned short* __restrict__ A,
                                            const unsigned short* __restrict__ BT,
                                            unsigned short* __restrict__ Cb,
                                            int k0g) {
    const int N = 1024;
    __shared__ __align__(16) unsigned short L[2][4][256 * 32];   // 128 KB
    int tid = threadIdx.x;
    int lane = tid & 63;
    int w = tid >> 6;
    int wm = (w >> 2) * 128, wn = (w & 3) * 64;
    int m0 = blockIdx.y * 256, n0 = blockIdx.x * 256;
    int hi = lane >> 4;
    int l15 = lane & 15;

    int c0 = tid, c1 = tid + 512;
    int r0 = c0 >> 2, kh0 = ((c0 & 3) - (r0 >> 1)) & 3;
    int r1 = c1 >> 2, kh1 = ((c1 & 3) - (r1 >> 1)) & 3;
    const unsigned short* aS0 = A  + (size_t)(m0 + r0) * LD + k0g + kh0 * 8;
    const unsigned short* aS1 = A  + (size_t)(m0 + r1) * LD + k0g + kh1 * 8;
    const unsigned short* bS0 = BT + (size_t)(n0 + r0) * LD + k0g + kh0 * 8;
    const unsigned short* bS1 = BT + (size_t)(n0 + r1) * LD + k0g + kh1 * 8;

    int aoff[8], boff[4];
    #pragma unroll
    for (int i = 0; i < 8; i++) {
        int m = wm + i * 16 + l15;
        aoff[i] = m * 32 + (((hi + (m >> 1)) & 3) * 8);
    }
    #pragma unroll
    for (int j = 0; j < 4; j++) {
        int n = wn + j * 16 + l15;
        boff[j] = n * 32 + (((hi + (n >> 1)) & 3) * 8);
    }

    f32x4 acc[8][4];
    #pragma unroll
    for (int i = 0; i < 8; i++)
        #pragma unroll
        for (int j = 0; j < 4; j++)
            acc[i][j] = (f32x4){0.f, 0.f, 0.f, 0.f};

#define STG8(kt, bf, rg) do {                                         \
        int _go = (kt) * 64 + ((rg) >> 1) * 32;                       \
        unsigned short* _d = &L[bf][rg][0];                           \
        if ((rg) & 1) { gl2lds16(bS0 + _go, _d + c0 * 8);             \
                        gl2lds16(bS1 + _go, _d + c1 * 8); }           \
        else          { gl2lds16(aS0 + _go, _d + c0 * 8);             \
                        gl2lds16(aS1 + _go, _d + c1 * 8); }           \
    } while (0)

    STG8(0, 0, 0); STG8(0, 0, 1); STG8(0, 0, 2); STG8(0, 0, 3);
    asm volatile("s_waitcnt vmcnt(4)" ::: "memory");
    __builtin_amdgcn_s_barrier();

    for (int t = 0; t < NT; t++) {
        int rd = t & 1, st = rd ^ 1;
        bool stg = (t + 1 < NT);
        const unsigned short* A0 = &L[rd][0][0];
        const unsigned short* B0 = &L[rd][1][0];
        const unsigned short* A1 = &L[rd][2][0];
        const unsigned short* B1 = &L[rd][3][0];
        bf16x8 af[8], bfr[4];

        asm volatile("" ::: "memory");
        #pragma unroll
        for (int i = 0; i < 8; i++) af[i] = *(const bf16x8*)&A0[aoff[i]];
        #pragma unroll
        for (int j = 0; j < 4; j++) bfr[j] = *(const bf16x8*)&B0[boff[j]];
        if (stg) { STG8(t + 1, st, 0); STG8(t + 1, st, 1); }
        __builtin_amdgcn_s_setprio(1);
        #pragma unroll
        for (int i = 0; i < 8; i++)
            #pragma unroll
            for (int j = 0; j < 4; j++)
                acc[i][j] = __builtin_amdgcn_mfma_f32_16x16x32_bf16(af[i], bfr[j], acc[i][j], 0, 0, 0);
        __builtin_amdgcn_s_setprio(0);
        if (stg) {
            asm volatile("s_waitcnt vmcnt(4)" ::: "memory");
        } else {
            asm volatile("s_waitcnt vmcnt(0)" ::: "memory");
        }
        __builtin_amdgcn_s_barrier();

        asm volatile("" ::: "memory");
        #pragma unroll
        for (int i = 0; i < 8; i++) af[i] = *(const bf16x8*)&A1[aoff[i]];
        #pragma unroll
        for (int j = 0; j < 4; j++) bfr[j] = *(const bf16x8*)&B1[boff[j]];
        if (stg) { STG8(t + 1, st, 2); STG8(t + 1, st, 3); }
        __builtin_amdgcn_s_setprio(1);
        #pragma unroll
        for (int i = 0; i < 8; i++)
            #pragma unroll
            for (int j = 0; j < 4; j++)
                acc[i][j] = __builtin_amdgcn_mfma_f32_16x16x32_bf16(af[i], bfr[j], acc[i][j], 0, 0, 0);
        __builtin_amdgcn_s_setprio(0);
        if (stg) {
            asm volatile("s_waitcnt vmcnt(4)" ::: "memory");
            __builtin_amdgcn_s_barrier();
        }
    }
#undef STG8

    #pragma unroll
    for (int i = 0; i < 8; i++) {
        #pragma unroll
        for (int j = 0; j < 4; j++) {
            int col = n0 + wn + j * 16 + l15;
            #pragma unroll
            for (int r = 0; r < 4; r++) {
                int row = m0 + wm + i * 16 + hi * 4 + r;
                Cb[(size_t)row * N + col] = f2bf(acc[i][j][r]);
            }
        }
    }
}

__global__ __launch_bounds__(512, 2) void gemm_qkv_mfma(const unsigned short* __restrict__ A,
                                                        const unsigned short* __restrict__ BT0,
                                                        const unsigned short* __restrict__ BT1,
                                                        const unsigned short* __restrict__ BT2,
                                                        unsigned short* __restrict__ C0,
                                                        unsigned short* __restrict__ C1,
                                                        unsigned short* __restrict__ C2) {
    const unsigned short* BT = (blockIdx.z == 0) ? BT0 : (blockIdx.z == 1) ? BT1 : BT2;
    unsigned short* C = (blockIdx.z == 0) ? C0 : (blockIdx.z == 1) ? C1 : C2;
    gemm2h_core<1024, 16>(A, BT, C, 0);
}

__global__ __launch_bounds__(512, 2) void gemm_out_mfma(const unsigned short* __restrict__ A,
                                                        const unsigned short* __restrict__ BT,
                                                        unsigned short* __restrict__ P0,
                                                        unsigned short* __restrict__ P1,
                                                        unsigned short* __restrict__ P2,
                                                        unsigned short* __restrict__ P3) {
    unsigned short* P = (blockIdx.z == 0) ? P0 : (blockIdx.z == 1) ? P1
                      : (blockIdx.z == 2) ? P2 : P3;
    gemm2h_core<2048, 8>(A, BT, P, blockIdx.z * 512);
}

__global__ __launch_bounds__(256) void out_reduce_kernel(const float* __restrict__ x,
                                                         const unsigned short* __restrict__ P0,
                                                         const unsigned short* __restrict__ P1,
                                                         const unsigned short* __restrict__ P2,
                                                         const unsigned short* __restrict__ P3,
                                                         float* __restrict__ out) {
    int g = blockIdx.x * 256 + threadIdx.x;
    size_t e = (size_t)g * 4;
    float4 xv = *(const float4*)&x[e];
    ushort4 a = *(const ushort4*)&P0[e];
    ushort4 b = *(const ushort4*)&P1[e];
    ushort4 c = *(const ushort4*)&P2[e];
    ushort4 d = *(const ushort4*)&P3[e];
    float4 o;
    o.x = xv.x + bf2f(a.x) + bf2f(b.x) + bf2f(c.x) + bf2f(d.x);
    o.y = xv.y + bf2f(a.y) + bf2f(b.y) + bf2f(c.y) + bf2f(d.y);
    o.z = xv.z + bf2f(a.z) + bf2f(b.z) + bf2f(c.z) + bf2f(d.z);
    o.w = xv.w + bf2f(a.w) + bf2f(b.w) + bf2f(c.w) + bf2f(d.w);
    *(float4*)&out[e] = o;
}

// ---------------------------------------------------------------------------
// Linear attention constants
// ---------------------------------------------------------------------------
#define PHI 160
#define NCH 32
#define KVROWS 65
#define CH_STRIDE ((size_t)32 * KVROWS * PHI)
#define KSTR 72   // staged raw K/Q row stride (conflict-free)
#define FSTR 18   // kf_l/qf_l row stride: 36B = 9 dwords -> 2 lanes/bank (free)

// ---------------------------------------------------------------------------
// FUSED: sliding-window attention (blockIdx.x < 32) + lin_kv (>= 32).
// ---------------------------------------------------------------------------
__global__ __launch_bounds__(256) void win_linkv_kernel(const unsigned short* __restrict__ q_bf,
                                                        const unsigned short* __restrict__ k_bf,
                                                        const float* __restrict__ Wkf,
                                                        const unsigned short* __restrict__ v_bf,
                                                        unsigned short* __restrict__ cat_bf,
                                                        unsigned short* __restrict__ kvbuf) {
    __shared__ __align__(16) unsigned short POOL[21136];   // 42.3 KB
    __shared__ float sclut[136];
    int bh = blockIdx.y;
    int h = bh & 15;
    int b = bh >> 4;
    int tid = threadIdx.x;
    int lane = tid & 63;

    if (blockIdx.x < TT / 64) {
        // =================== WIN path ===================
        unsigned short* Qs = POOL;
        unsigned short* Ks = POOL + 4096;
        unsigned short* Vt = POOL + 12288;
        unsigned short* Pl = POOL;
        int qtile = blockIdx.x;
        int wv = tid >> 6;
        int qr0 = wv * 16;
        int t0 = qtile * 64;
        int k0 = t0 - 64;

        #pragma unroll
        for (int half = 0; half < 2; half++) {
            int slot = tid + half * 256;
            int row = slot >> 3, pos = slot & 7;
            int o = (pos - row) & 7;
            gl2lds16(q_bf + (size_t)(b * TT + t0 + row) * (NH * HD) + h * HD + o * 8,
                     &Qs[slot * 8]);
        }
        #pragma unroll
        for (int qd = 0; qd < 4; qd++) {
            int slot = tid + qd * 256;
            int row = slot >> 3, pos = slot & 7;
            int o = (pos - row) & 7;
            int kg = k0 + row;
            if (kg >= 0) {
                gl2lds16(k_bf + (size_t)(b * TT + kg) * (NH * HD) + h * HD + o * 8,
                         &Ks[slot * 8]);
            } else {
                uint4 z = {0, 0, 0, 0};
                *(uint4*)&Ks[slot * 8] = z;
            }
        }
        {
            int kk = tid & 127;
            int dh = tid >> 7;
            int kg = k0 + kk;
            unsigned short tmp[32];
            if (kg >= 0) {
                size_t base = (size_t)(b * TT + kg) * (NH * HD) + h * HD + dh * 32;
                *(uint4*)&tmp[0]  = *(const uint4*)&v_bf[base];
                *(uint4*)&tmp[8]  = *(const uint4*)&v_bf[base + 8];
                *(uint4*)&tmp[16] = *(const uint4*)&v_bf[base + 16];
                *(uint4*)&tmp[24] = *(const uint4*)&v_bf[base + 24];
            } else {
                #pragma unroll
                for (int d = 0; d < 32; d++) tmp[d] = 0;
            }
            int o = kk >> 3, klow = kk & 7;
            #pragma unroll
            for (int d = 0; d < 32; d++) {
                int dim = dh * 32 + d;
                Vt[dim * 128 + ((o + dim) & 15) * 8 + klow] = tmp[d];
            }
        }
        __syncthreads();

        int hi = lane >> 4;
        int lan15 = lane & 15;
        f32x4 sc[8];
        #pragma unroll
        for (int nt = 0; nt < 8; nt++) sc[nt] = (f32x4){0.f, 0.f, 0.f, 0.f};
        #pragma unroll
        for (int ks = 0; ks < 2; ks++) {
            int m = qr0 + lan15;
            int oA = ks * 4 + hi;
            bf16x8 a = *(const bf16x8*)&Qs[m * 64 + ((oA + m) & 7) * 8];
            #pragma unroll
            for (int nt = 0; nt < 8; nt++) {
                int n = nt * 16 + lan15;
                bf16x8 bb = *(const bf16x8*)&Ks[n * 64 + ((oA + n) & 7) * 8];
                sc[nt] = __builtin_amdgcn_mfma_f32_16x16x32_bf16(a, bb, sc[nt], 0, 0, 0);
            }
        }

        float lrow[4];
        #pragma unroll
        for (int r = 0; r < 4; r++) {
            int tq = t0 + qr0 + hi * 4 + r;
            float mx = -1e30f;
            #pragma unroll
            for (int nt = 0; nt < 8; nt++) {
                int s = k0 + nt * 16 + lan15;
                bool ok = (s >= 0) && (s <= tq) && (s >= tq - WIN);
                float vv = ok ? sc[nt][r] * 0.125f : -1e30f;
                sc[nt][r] = vv;
                mx = fmaxf(mx, vv);
            }
            #pragma unroll
            for (int off = 1; off < 16; off <<= 1) mx = fmaxf(mx, __shfl_xor(mx, off, 64));
            float ls = 0.f;
            #pragma unroll
            for (int nt = 0; nt < 8; nt++) {
                float e = __expf(sc[nt][r] - mx);
                sc[nt][r] = e;
                ls += e;
            }
            #pragma unroll
            for (int off = 1; off < 16; off <<= 1) ls += __shfl_xor(ls, off, 64);
            lrow[r] = ls;
        }

        __syncthreads();   // Qs/Ks reads complete in ALL waves before Pl overwrite

        #pragma unroll
        for (int nt = 0; nt < 8; nt++) {
            #pragma unroll
            for (int r = 0; r < 4; r++) {
                int row = qr0 + hi * 4 + r;
                int col = nt * 16 + lan15;
                Pl[row * 128 + (((col >> 3) + row) & 15) * 8 + (col & 7)] = f2bf(sc[nt][r]);
            }
        }
        __syncthreads();

        f32x4 y[4];
        #pragma unroll
        for (int nt = 0; nt < 4; nt++) y[nt] = (f32x4){0.f, 0.f, 0.f, 0.f};
        #pragma unroll
        for (int ks = 0; ks < 4; ks++) {
            int m = qr0 + lan15;
            int oA = ks * 4 + hi;
            bf16x8 a = *(const bf16x8*)&Pl[m * 128 + ((oA + m) & 15) * 8];
            #pragma unroll
            for (int nt = 0; nt < 4; nt++) {
                int n = nt * 16 + lan15;
                bf16x8 bb = *(const bf16x8*)&Vt[n * 128 + ((oA + n) & 15) * 8];
                y[nt] = __builtin_amdgcn_mfma_f32_16x16x32_bf16(a, bb, y[nt], 0, 0, 0);
            }
        }

        #pragma unroll
        for (int nt = 0; nt < 4; nt++) {
            #pragma unroll
            for (int r = 0; r < 4; r++) {
                int row = qr0 + hi * 4 + r;
                int dim = nt * 16 + lan15;
                cat_bf[(size_t)(b * TT + t0 + row) * (2 * DM) + DM + h * HD + dim] =
                    f2bf(y[nt][r] / lrow[r]);
            }
        }
        return;
    }

    // =================== LIN_KV path ===================
    {
        unsigned short* kf_l = POOL;                 // 64 x FSTR
        unsigned short* PhiT = POOL + 1152;
        unsigned short* Vt   = POOL + 15744;
        unsigned short* iu   = POOL + 20864;
        unsigned short* ju   = POOL + 21000;
        int c = blockIdx.x - TT / 64;
        int w = tid >> 6;
        int hi = lane >> 4, l15 = lane & 15;

        unsigned short* ks_l = &PhiT[0];            // 64xKSTR staged K rows
        float* Wf = (float*)&PhiT[64 * KSTR];       // 64x16 f32 weights

        if (tid < 136) {
            int qq = tid, i = 0;
            while (qq >= 16 - i) { qq -= 16 - i; i++; }
            iu[tid] = (unsigned short)i; ju[tid] = (unsigned short)(i + qq);
            sclut[tid] = (qq == 0) ? 0.5f : 0.70710678118654752f;
        }
        {
            int r = tid >> 2, q16 = (tid & 3) * 16;
            size_t gb = ((size_t)(b * TT + c * 64 + r)) * DM + h * HD + q16;
            *(uint4*)&ks_l[r * KSTR + q16]     = *(const uint4*)&k_bf[gb];
            *(uint4*)&ks_l[r * KSTR + q16 + 8] = *(const uint4*)&k_bf[gb + 8];
        }
        ((float4*)Wf)[tid] = ((const float4*)Wkf)[tid];
        {
            int p = tid & 31, dq = (tid >> 5) * 8;
            size_t base0 = ((size_t)(b * TT + c * 64 + 2 * p)) * DM + h * HD + dq;
            unsigned short a[8], bq[8];
            *(uint4*)a  = *(const uint4*)&v_bf[base0];
            *(uint4*)bq = *(const uint4*)&v_bf[base0 + DM];
            int colo = p >> 2, coll = (2 * p) & 7;
            #pragma unroll
            for (int d = 0; d < 8; d++) {
                int row = dq + d;
                ushort2 u; u.x = a[d]; u.y = bq[d];
                *(ushort2*)&Vt[row * 64 + ((colo + row) & 7) * 8 + coll] = u;
            }
            #pragma unroll
            for (int i = 0; i < 4; i++) {
                int e = tid + i * 256;
                Vt[(64 + (e >> 6)) * 64 + (e & 63)] = 0x3F80;
            }
        }
        __syncthreads();
        {
            int r = tid >> 2, f0 = (tid & 3) * 4;
            const unsigned short* kr = &ks_l[r * KSTR];
            float a0 = 0.f, a1 = 0.f, a2 = 0.f, a3 = 0.f;
            #pragma unroll 8
            for (int d = 0; d < HD; d++) {
                float kv = bf2f(kr[d]);
                const float* wr = &Wf[d * FEAT + f0];
                a0 += kv * wr[0]; a1 += kv * wr[1]; a2 += kv * wr[2]; a3 += kv * wr[3];
            }
            ushort2 o01; o01.x = f2bf(a0); o01.y = f2bf(a1);
            ushort2 o23; o23.x = f2bf(a2); o23.y = f2bf(a3);
            *(ushort2*)&kf_l[r * FSTR + f0]     = o01;
            *(ushort2*)&kf_l[r * FSTR + f0 + 2] = o23;
        }
        __syncthreads();
        {
            int s = tid & 63, fb = tid >> 6;
            const unsigned short* krow = &kf_l[s * FSTR];
            for (int it = 0; it < 40; it++) {
                int f = fb * 40 + it;
                float val;
                if (f == 0) val = 1.f;
                else if (f < 17) val = bf2f(krow[f - 1]);
                else if (f < 153) { int qq = f - 17; val = bf2f(krow[iu[qq]]) * bf2f(krow[ju[qq]]) * sclut[qq]; }
                else val = 0.f;   // f in [153,160): zero padding (guard load-bearing!)
                PhiT[f * 76 + s] = f2bf(val);
            }
        }
        __syncthreads();
        f32x4 acc[5][3];
        #pragma unroll
        for (int m = 0; m < 5; m++)
            #pragma unroll
            for (int j = 0; j < 3; j++) acc[m][j] = (f32x4){0.f, 0.f, 0.f, 0.f};
        #pragma unroll
        for (int ks = 0; ks < 2; ks++) {
            bf16x8 bfrag[3];
            #pragma unroll
            for (int j = 0; j < 3; j++)
                bfrag[j] = *(const bf16x8*)&PhiT[((3 * w + j) * 16 + l15) * 76 + ks * 32 + hi * 8];
            #pragma unroll
            for (int m = 0; m < 5; m++) {
                int mrow = m * 16 + l15;
                bf16x8 afrag = *(const bf16x8*)&Vt[mrow * 64 + (((ks * 4 + hi) + mrow) & 7) * 8];
                #pragma unroll
                for (int j = 0; j < 3; j++)
                    acc[m][j] = __builtin_amdgcn_mfma_f32_16x16x32_bf16(afrag, bfrag[j], acc[m][j], 0, 0, 0);
            }
        }
        size_t obase = ((size_t)c * 32 + bh) * (KVROWS * PHI);
        #pragma unroll
        for (int m = 0; m < 5; m++) {
            #pragma unroll
            for (int j = 0; j < 3; j++) {
                int f = (3 * w + j) * 16 + l15;
                if (f >= PHI) continue;
                #pragma unroll
                for (int r = 0; r < 4; r++) {
                    int row = m * 16 + hi * 4 + r;
                    if (row >= KVROWS) continue;
                    kvbuf[obase + row * PHI + f] = f2bf(acc[m][j][r]);
                }
            }
        }
    }
}

// Phase C: in-place exclusive prefix over chunks. grid (41, 32 bh)
__global__ __launch_bounds__(256) void lin_scan_kernel(unsigned short* __restrict__ kvbuf) {
    int e = blockIdx.x * 256 + threadIdx.x;
    int bh = blockIdx.y;
    if (e >= KVROWS * PHI) return;
    float acc = 0.f;
    size_t off = (size_t)bh * (KVROWS * PHI) + e;
    for (int c = 0; c < NCH; c++) {
        float vv = bf2f(kvbuf[off]);
        kvbuf[off] = f2bf(acc);
        acc += vv;
        off += CH_STRIDE;
    }
}

// Phase D: outputs. grid (32 chunks, 32 bh), 256 threads (R14 form).
__global__ __launch_bounds__(256) void lin_out_kernel(const unsigned short* __restrict__ q_bf,
                                                      const unsigned short* __restrict__ k_bf,
                                                      const float* __restrict__ Wqf,
                                                      const float* __restrict__ Wkf,
                                                      const unsigned short* __restrict__ v_bf,
                                                      const unsigned short* __restrict__ kvbuf,
                                                      unsigned short* __restrict__ cat_bf) {
    int c = blockIdx.x, bh = blockIdx.y;
    int h = bh & 15, b = bh >> 4;
    int tid = threadIdx.x, lane = tid & 63, w = tid >> 6;
    int hi = lane >> 4, l15 = lane & 15;

    __shared__ unsigned short qf_l[64 * FSTR];
    __shared__ __align__(16) unsigned short kf_lb[64 * 34];   // cols 16..31 zero
    __shared__ __align__(16) unsigned short KVS_l[80 * 164];  // rows 65..79 zero
    __shared__ __align__(16) unsigned short Vt[80 * 64];      // swizzled + ones rows
    __shared__ __align__(16) unsigned short Phi_l[64 * 164];  // [token][f]
    __shared__ __align__(16) unsigned short P_l[64 * 64];     // swizzled
    __shared__ unsigned short iu[136], ju[136];
    __shared__ float sclut[136];

    unsigned short* qs_l = &KVS_l[0];              // 64xKSTR staged Q rows
    unsigned short* ks_l = &KVS_l[64 * KSTR];      // 64xKSTR staged K rows
    float* Wq_s = (float*)&Phi_l[0];               // 4KB
    float* Wk_s = (float*)&Phi_l[2048];            // 4KB

    if (tid < 136) {
        int qq = tid, i = 0;
        while (qq >= 16 - i) { qq -= 16 - i; i++; }
        iu[tid] = (unsigned short)i; ju[tid] = (unsigned short)(i + qq);
        sclut[tid] = (qq == 0) ? 0.5f : 0.70710678118654752f;
    }
    {   // stage Q and K rows coalesced (stride KSTR)
        int r = tid >> 2, q16 = (tid & 3) * 16;
        size_t gq = ((size_t)(b * TT + c * 64 + r)) * DM + h * HD + q16;
        *(uint4*)&qs_l[r * KSTR + q16]     = *(const uint4*)&q_bf[gq];
        *(uint4*)&qs_l[r * KSTR + q16 + 8] = *(const uint4*)&q_bf[gq + 8];
        *(uint4*)&ks_l[r * KSTR + q16]     = *(const uint4*)&k_bf[gq];
        *(uint4*)&ks_l[r * KSTR + q16 + 8] = *(const uint4*)&k_bf[gq + 8];
    }
    ((float4*)Wq_s)[tid] = ((const float4*)Wqf)[tid];
    ((float4*)Wk_s)[tid] = ((const float4*)Wkf)[tid];
    {   // stage V^T swizzled + ones rows
        int p = tid & 31, dq = (tid >> 5) * 8;
        size_t base0 = ((size_t)(b * TT + c * 64 + 2 * p)) * DM + h * HD + dq;
        unsigned short a[8], bq[8];
        *(uint4*)a  = *(const uint4*)&v_bf[base0];
        *(uint4*)bq = *(const uint4*)&v_bf[base0 + DM];
        int colo = p >> 2, coll = (2 * p) & 7;
        #pragma unroll
        for (int d = 0; d < 8; d++) {
            int row = dq + d;
            ushort2 u; u.x = a[d]; u.y = bq[d];
            *(ushort2*)&Vt[row * 64 + ((colo + row) & 7) * 8 + coll] = u;
        }
        #pragma unroll
        for (int i = 0; i < 4; i++) {
            int e = tid + i * 256;
            Vt[(64 + (e >> 6)) * 64 + (e & 63)] = 0x3F80;
        }
    }
    __syncthreads();
    {   // compute qf_l and kf_lb (fp32, d ascending)
        int r = tid >> 2, f0 = (tid & 3) * 4;
        const unsigned short* qr = &qs_l[r * KSTR];
        const unsigned short* kr = &ks_l[r * KSTR];
        float qa0=0.f,qa1=0.f,qa2=0.f,qa3=0.f, ka0=0.f,ka1=0.f,ka2=0.f,ka3=0.f;
        #pragma unroll 8
        for (int d = 0; d < HD; d++) {
            float qv = bf2f(qr[d]);
            float kv = bf2f(kr[d]);
            const float* wq = &Wq_s[d * FEAT + f0];
            const float* wk = &Wk_s[d * FEAT + f0];
            qa0 += qv * wq[0]; qa1 += qv * wq[1]; qa2 += qv * wq[2]; qa3 += qv * wq[3];
            ka0 += kv * wk[0]; ka1 += kv * wk[1]; ka2 += kv * wk[2]; ka3 += kv * wk[3];
        }
        ushort2 q01; q01.x = f2bf(qa0); q01.y = f2bf(qa1);
        ushort2 q23; q23.x = f2bf(qa2); q23.y = f2bf(qa3);
        *(ushort2*)&qf_l[r * FSTR + f0]     = q01;
        *(ushort2*)&qf_l[r * FSTR + f0 + 2] = q23;
        ushort4 ok; ok.x = f2bf(ka0); ok.y = f2bf(ka1); ok.z = f2bf(ka2); ok.w = f2bf(ka3);
        *(ushort4*)&kf_lb[r * 34 + f0] = ok;
        ushort4 z4 = {0, 0, 0, 0};
        *(ushort4*)&kf_lb[r * 34 + 16 + f0] = z4;
    }
    __syncthreads();
    {   // stage KVS rows 0..64 (overwrites qs/ks scratch - post-sync)
        size_t gbase = ((size_t)c * 32 + bh) * (KVROWS * PHI);
        #pragma unroll
        for (int i = 0; i < 11; i++) {
            int e4 = tid + i * 256;
            if (e4 < KVROWS * 40) {
                int r = e4 / 40, q4 = (e4 % 40) * 4;
                *(ushort4*)&KVS_l[r * 164 + q4] =
                    *(const ushort4*)&kvbuf[gbase + r * PHI + q4];
            }
        }
        #pragma unroll
        for (int i = 0; i < 3; i++) {
            int e4 = tid + i * 256;
            if (e4 < 15 * 40) {
                int r = 65 + e4 / 40, q4 = (e4 % 40) * 4;
                ushort4 z4 = {0, 0, 0, 0};
                *(ushort4*)&KVS_l[r * 164 + q4] = z4;
            }
        }
    }
    {   // build Phi_l[token][f] (overwrites Wq_s/Wk_s scratch - post-sync)
        int s = tid & 63, fb = tid >> 6;
        const unsigned short* qrow = &qf_l[s * FSTR];
        for (int it = 0; it < 40; it++) {
            int f = fb * 40 + it;
            float val;
            if (f == 0) val = 1.f;
            else if (f < 17) val = bf2f(qrow[f - 1]);
            else if (f < 153) { int qq = f - 17; val = bf2f(qrow[iu[qq]]) * bf2f(qrow[ju[qq]]) * sclut[qq]; }
            else val = 0.f;   // f in [153,160): zero padding (guard load-bearing!)
            Phi_l[s * 164 + f] = f2bf(val);
        }
    }
    __syncthreads();

    f32x4 acc[5];
    #pragma unroll
    for (int n = 0; n < 5; n++) acc[n] = (f32x4){0.f, 0.f, 0.f, 0.f};

    int t_m = w * 16 + l15;

    // GEMM1: Phi (LDS) x KVS
    #pragma unroll
    for (int ks = 0; ks < 5; ks++) {
        bf16x8 af = *(const bf16x8*)&Phi_l[t_m * 164 + ks * 32 + hi * 8];
        #pragma unroll
        for (int n = 0; n < 5; n++) {
            bf16x8 bb = *(const bf16x8*)&KVS_l[(n * 16 + l15) * 164 + ks * 32 + hi * 8];
            acc[n] = __builtin_amdgcn_mfma_f32_16x16x32_bf16(af, bb, acc[n], 0, 0, 0);
        }
    }

    // intra-chunk scores: S = (1 + qf.kf/2)^2, causal (diag included)
    {
        union { unsigned short u[8]; bf16x8 v; } aq;
        #pragma unroll
        for (int j = 0; j < 8; j++) {
            int f = hi * 8 + j;
            aq.u[j] = (f < 16) ? qf_l[t_m * FSTR + f] : (unsigned short)0;
        }
        #pragma unroll
        for (int n = 0; n < 4; n++) {
            bf16x8 bk = *(const bf16x8*)&kf_lb[(n * 16 + l15) * 34 + hi * 8];
            f32x4 zv = {0.f, 0.f, 0.f, 0.f};
            f32x4 sc = __builtin_amdgcn_mfma_f32_16x16x32_bf16(aq.v, bk, zv, 0, 0, 0);
            int sl = n * 16 + l15;
            #pragma unroll
            for (int r = 0; r < 4; r++) {
                int rl = w * 16 + hi * 4 + r;
                float sv = 1.f + 0.5f * sc[r];
                sv = sv * sv;
                if (sl > rl) sv = 0.f;
                P_l[rl * 64 + (((sl >> 3) + rl) & 7) * 8 + (sl & 7)] = f2bf(sv);
            }
        }
    }
    __syncthreads();

    // GEMM2: P x Vt (y into cols 0..63, z into col 64 via ones rows)
    #pragma unroll
    for (int ks = 0; ks < 2; ks++) {
        int oA = ks * 4 + hi;
        bf16x8 a = *(const bf16x8*)&P_l[t_m * 64 + ((oA + t_m) & 7) * 8];
        #pragma unroll
        for (int n = 0; n < 5; n++) {
            int nrow = n * 16 + l15;
            bf16x8 bb = *(const bf16x8*)&Vt[nrow * 64 + ((oA + nrow) & 7) * 8];
            acc[n] = __builtin_amdgcn_mfma_f32_16x16x32_bf16(a, bb, acc[n], 0, 0, 0);
        }
    }

    // epilogue: z lives in col 64 (l15==0 of acc[4]); broadcast per row
    #pragma unroll
    for (int r = 0; r < 4; r++) {
        float zz = __shfl(acc[4][r], (lane & 48), 64);
        int token = c * 64 + w * 16 + hi * 4 + r;
        #pragma unroll
        for (int n = 0; n < 4; n++) {
            int d = n * 16 + l15;
            cat_bf[((size_t)(b * TT + token)) * (2 * DM) + h * HD + d] =
                f2bf(acc[n][r] / (zz + 1e-6f));
        }
    }
}

// ---------------------------------------------------------------------------
extern "C" void kernel_launch(void* const* d_in, const int* in_sizes, int n_in,
                              void* d_out, int out_size, void* d_ws, size_t ws_size,
                              hipStream_t stream) {
    const float* x      = (const float*)d_in[0];
    const float* norm_w = (const float*)d_in[1];
    const float* Wq     = (const float*)d_in[2];
    const float* Wk     = (const float*)d_in[3];
    const float* Wv     = (const float*)d_in[4];
    const float* Wqf    = (const float*)d_in[5];
    const float* Wkf    = (const float*)d_in[6];
    const float* Wout   = (const float*)d_in[7];
    float* out = (float*)d_out;

    char* p = (char*)d_ws;
    unsigned short* h_bf = (unsigned short*)p; p += (size_t)RTOT * DM * 2;       // 8 MB
    unsigned short* WqT  = (unsigned short*)p; p += (size_t)DM * DM * 2;         // 2 MB
    unsigned short* WkT  = (unsigned short*)p; p += (size_t)DM * DM * 2;
    unsigned short* WvT  = (unsigned short*)p; p += (size_t)DM * DM * 2;
    unsigned short* WoT  = (unsigned short*)p; p += (size_t)DM * 2 * DM * 2;     // 4 MB
    unsigned short* q_bf = (unsigned short*)p; p += (size_t)RTOT * DM * 2;       // 8 MB
    unsigned short* k_bf = (unsigned short*)p; p += (size_t)RTOT * DM * 2;
    unsigned short* v_bf = (unsigned short*)p; p += (size_t)RTOT * DM * 2;
    p += (size_t)RTOT * NH * FEAT * 2 * 2;   // (former qf/kf buffers - unused)
    unsigned short* cat_bf = (unsigned short*)p; p += (size_t)RTOT * 2 * DM * 2;   // 16 MB
    unsigned short* kvbuf  = (unsigned short*)p; p += (size_t)NCH * 32 * KVROWS * PHI * 2; // 21.3 MB
    unsigned short* P0 = (unsigned short*)p; p += (size_t)RTOT * DM * 2;           // 8 MB
    unsigned short* P1 = (unsigned short*)p; p += (size_t)RTOT * DM * 2;           // 8 MB
    unsigned short* P2 = h_bf;
    unsigned short* P3 = q_bf;

    prep_kernel<<<RTOT + 2048, 256, 0, stream>>>(x, norm_w, h_bf,
                                                 Wq, Wk, Wv, Wout, WqT, WkT, WvT, WoT);
    gemm_qkv_mfma<<<dim3(4, 16, 3), 512, 0, stream>>>(h_bf, WqT, WkT, WvT, q_bf, k_bf, v_bf);
    win_linkv_kernel<<<dim3(2 * (TT / 64), BB * NH), 256, 0, stream>>>(q_bf, k_bf, Wkf, v_bf, cat_bf, kvbuf);
    lin_scan_kernel<<<dim3((KVROWS * PHI + 255) / 256, BB * NH), 256, 0, stream>>>(kvbuf);
    lin_out_kernel<<<dim3(NCH, BB * NH), 256, 0, stream>>>(q_bf, k_bf, Wqf, Wkf, v_bf, kvbuf, cat_bf);
    gemm_out_mfma<<<dim3(4, 16, 4), 512, 0, stream>>>(cat_bf, WoT, P0, P1, P2, P3);
    out_reduce_kernel<<<RTOT * DM / 1024, 256, 0, stream>>>(x, P0, P1, P2, P3, out);
}

// Round 18
// 229.961 us; speedup vs baseline: 1.0496x; 1.0210x over previous
//
#include <hip/hip_runtime.h>
#include <math.h>

// Problem constants
#define BB 2
#define TT 2048
#define DM 1024
#define NH 16
#define HD 64
#define FEAT 16
#define WIN 64
#define RTOT (BB*TT)        // 4096 rows

typedef __bf16 bf16x8 __attribute__((ext_vector_type(8)));
typedef float  f32x4  __attribute__((ext_vector_type(4)));

__device__ __forceinline__ unsigned short f2bf(float f) {
    union { float f; unsigned u; } v; v.f = f;
    unsigned r = v.u + 0x7FFFu + ((v.u >> 16) & 1u);   // RNE
    return (unsigned short)(r >> 16);
}
__device__ __forceinline__ float bf2f(unsigned short u) {
    union { unsigned u; float f; } v; v.u = ((unsigned)u) << 16; return v.f;
}

__device__ __forceinline__ void gl2lds16(const void* g, void* l) {
    __builtin_amdgcn_global_load_lds(
        (const __attribute__((address_space(1))) void*)g,
        (__attribute__((address_space(3))) void*)l, 16, 0, 0);
}

// ---------------------------------------------------------------------------
// Kernel 1 (merged): RMSNorm (blocks 0..4095) + weight transpose/bf16-cast.
// R18: trimmed 768 no-op blocks (z<3 by>=16 early-exits); z=0..2 get 256
// blocks, z=3 gets 512. Work otherwise identical.
// ---------------------------------------------------------------------------
__global__ __launch_bounds__(256) void prep_kernel(const float* __restrict__ x,
                                                   const float* __restrict__ w,
                                                   unsigned short* __restrict__ h_bf,
                                                   const float* __restrict__ W0,
                                                   const float* __restrict__ W1,
                                                   const float* __restrict__ W2,
                                                   const float* __restrict__ W3,
                                                   unsigned short* __restrict__ T0,
                                                   unsigned short* __restrict__ T1,
                                                   unsigned short* __restrict__ T2,
                                                   unsigned short* __restrict__ T3) {
    __shared__ float red[4];
    __shared__ float tile[64][65];
    int bx = blockIdx.x;
    int tid = threadIdx.x;
    if (bx < RTOT) {
        int row = bx;
        const float4* xr = (const float4*)(x + (size_t)row * DM);
        float4 xv = xr[tid];
        float ss = xv.x*xv.x + xv.y*xv.y + xv.z*xv.z + xv.w*xv.w;
        #pragma unroll
        for (int off = 32; off > 0; off >>= 1) ss += __shfl_down(ss, off, 64);
        if ((tid & 63) == 0) red[tid >> 6] = ss;
        __syncthreads();
        float tot = red[0] + red[1] + red[2] + red[3];
        float scale = rsqrtf(tot * (1.0f / DM) + 1e-6f);
        float4 wv = ((const float4*)w)[tid];
        ushort4 o;
        o.x = f2bf(xv.x * scale * wv.x);
        o.y = f2bf(xv.y * scale * wv.y);
        o.z = f2bf(xv.z * scale * wv.z);
        o.w = f2bf(xv.w * scale * wv.w);
        *(ushort4*)&h_bf[(size_t)row * DM + tid * 4] = o;
        return;
    }
    // transpose blocks: t in [0,1280): z<3 -> 256 blocks each; z=3 -> 512
    int t = bx - RTOT;
    int z, rem;
    if (t < 768) { z = t >> 8; rem = t & 255; }
    else         { z = 3;      rem = t - 768; }
    int by = rem >> 4;
    int bxx = rem & 15;
    int K = (z == 3) ? 2048 : 1024;
    const int N = 1024;
    if (by * 64 >= K) return;
    const float* W = (z == 0) ? W0 : (z == 1) ? W1 : (z == 2) ? W2 : W3;
    unsigned short* WT = (z == 0) ? T0 : (z == 1) ? T1 : (z == 2) ? T2 : T3;
    int k0 = by * 64, n0 = bxx * 64;
    int r = tid >> 4, c4 = (tid & 15) * 4;
    #pragma unroll
    for (int i = 0; i < 4; i++) {
        float4 vv = *(const float4*)&W[(size_t)(k0 + r + i*16) * N + n0 + c4];
        tile[r + i*16][c4 + 0] = vv.x;
        tile[r + i*16][c4 + 1] = vv.y;
        tile[r + i*16][c4 + 2] = vv.z;
        tile[r + i*16][c4 + 3] = vv.w;
    }
    __syncthreads();
    int rn = tid >> 2, kq = (tid & 3) * 16;
    unsigned short u[16];
    #pragma unroll
    for (int i = 0; i < 16; i++) u[i] = f2bf(tile[kq + i][rn]);
    size_t base = (size_t)(n0 + rn) * K + k0 + kq;
    *(uint4*)&WT[base]     = *(uint4*)&u[0];
    *(uint4*)&WT[base + 8] = *(uint4*)&u[8];
}

// ---------------------------------------------------------------------------
// bf16 MFMA GEMM core: 256x256 tile, 8 waves, BK=64, 2-half schedule.
// (R14-measured-best configuration.)
// ---------------------------------------------------------------------------
template<int LD, int NT>
__device__ __forceinline__ void gemm2h_core(const unsigned short* __restrict__ A,
                                            const unsigned short* __restrict__ BT,
                                            unsigned short* __restrict__ Cb,
                                            int k0g) {
    const int N = 1024;
    __shared__ __align__(16) unsigned short L[2][4][256 * 32];   // 128 KB
    int tid = threadIdx.x;
    int lane = tid & 63;
    int w = tid >> 6;
    int wm = (w >> 2) * 128, wn = (w & 3) * 64;
    int m0 = blockIdx.y * 256, n0 = blockIdx.x * 256;
    int hi = lane >> 4;
    int l15 = lane & 15;

    int c0 = tid, c1 = tid + 512;
    int r0 = c0 >> 2, kh0 = ((c0 & 3) - (r0 >> 1)) & 3;
    int r1 = c1 >> 2, kh1 = ((c1 & 3) - (r1 >> 1)) & 3;
    const unsigned short* aS0 = A  + (size_t)(m0 + r0) * LD + k0g + kh0 * 8;
    const unsigned short* aS1 = A  + (size_t)(m0 + r1) * LD + k0g + kh1 * 8;
    const unsigned short* bS0 = BT + (size_t)(n0 + r0) * LD + k0g + kh0 * 8;
    const unsigned short* bS1 = BT + (size_t)(n0 + r1) * LD + k0g + kh1 * 8;

    int aoff[8], boff[4];
    #pragma unroll
    for (int i = 0; i < 8; i++) {
        int m = wm + i * 16 + l15;
        aoff[i] = m * 32 + (((hi + (m >> 1)) & 3) * 8);
    }
    #pragma unroll
    for (int j = 0; j < 4; j++) {
        int n = wn + j * 16 + l15;
        boff[j] = n * 32 + (((hi + (n >> 1)) & 3) * 8);
    }

    f32x4 acc[8][4];
    #pragma unroll
    for (int i = 0; i < 8; i++)
        #pragma unroll
        for (int j = 0; j < 4; j++)
            acc[i][j] = (f32x4){0.f, 0.f, 0.f, 0.f};

#define STG8(kt, bf, rg) do {                                         \
        int _go = (kt) * 64 + ((rg) >> 1) * 32;                       \
        unsigned short* _d = &L[bf][rg][0];                           \
        if ((rg) & 1) { gl2lds16(bS0 + _go, _d + c0 * 8);             \
                        gl2lds16(bS1 + _go, _d + c1 * 8); }           \
        else          { gl2lds16(aS0 + _go, _d + c0 * 8);             \
                        gl2lds16(aS1 + _go, _d + c1 * 8); }           \
    } while (0)

    STG8(0, 0, 0); STG8(0, 0, 1); STG8(0, 0, 2); STG8(0, 0, 3);
    asm volatile("s_waitcnt vmcnt(4)" ::: "memory");
    __builtin_amdgcn_s_barrier();

    for (int t = 0; t < NT; t++) {
        int rd = t & 1, st = rd ^ 1;
        bool stg = (t + 1 < NT);
        const unsigned short* A0 = &L[rd][0][0];
        const unsigned short* B0 = &L[rd][1][0];
        const unsigned short* A1 = &L[rd][2][0];
        const unsigned short* B1 = &L[rd][3][0];
        bf16x8 af[8], bfr[4];

        asm volatile("" ::: "memory");
        #pragma unroll
        for (int i = 0; i < 8; i++) af[i] = *(const bf16x8*)&A0[aoff[i]];
        #pragma unroll
        for (int j = 0; j < 4; j++) bfr[j] = *(const bf16x8*)&B0[boff[j]];
        if (stg) { STG8(t + 1, st, 0); STG8(t + 1, st, 1); }
        __builtin_amdgcn_s_setprio(1);
        #pragma unroll
        for (int i = 0; i < 8; i++)
            #pragma unroll
            for (int j = 0; j < 4; j++)
                acc[i][j] = __builtin_amdgcn_mfma_f32_16x16x32_bf16(af[i], bfr[j], acc[i][j], 0, 0, 0);
        __builtin_amdgcn_s_setprio(0);
        if (stg) {
            asm volatile("s_waitcnt vmcnt(4)" ::: "memory");
        } else {
            asm volatile("s_waitcnt vmcnt(0)" ::: "memory");
        }
        __builtin_amdgcn_s_barrier();

        asm volatile("" ::: "memory");
        #pragma unroll
        for (int i = 0; i < 8; i++) af[i] = *(const bf16x8*)&A1[aoff[i]];
        #pragma unroll
        for (int j = 0; j < 4; j++) bfr[j] = *(const bf16x8*)&B1[boff[j]];
        if (stg) { STG8(t + 1, st, 2); STG8(t + 1, st, 3); }
        __builtin_amdgcn_s_setprio(1);
        #pragma unroll
        for (int i = 0; i < 8; i++)
            #pragma unroll
            for (int j = 0; j < 4; j++)
                acc[i][j] = __builtin_amdgcn_mfma_f32_16x16x32_bf16(af[i], bfr[j], acc[i][j], 0, 0, 0);
        __builtin_amdgcn_s_setprio(0);
        if (stg) {
            asm volatile("s_waitcnt vmcnt(4)" ::: "memory");
            __builtin_amdgcn_s_barrier();
        }
    }
#undef STG8

    #pragma unroll
    for (int i = 0; i < 8; i++) {
        #pragma unroll
        for (int j = 0; j < 4; j++) {
            int col = n0 + wn + j * 16 + l15;
            #pragma unroll
            for (int r = 0; r < 4; r++) {
                int row = m0 + wm + i * 16 + hi * 4 + r;
                Cb[(size_t)row * N + col] = f2bf(acc[i][j][r]);
            }
        }
    }
}

__global__ __launch_bounds__(512, 2) void gemm_qkv_mfma(const unsigned short* __restrict__ A,
                                                        const unsigned short* __restrict__ BT0,
                                                        const unsigned short* __restrict__ BT1,
                                                        const unsigned short* __restrict__ BT2,
                                                        unsigned short* __restrict__ C0,
                                                        unsigned short* __restrict__ C1,
                                                        unsigned short* __restrict__ C2) {
    const unsigned short* BT = (blockIdx.z == 0) ? BT0 : (blockIdx.z == 1) ? BT1 : BT2;
    unsigned short* C = (blockIdx.z == 0) ? C0 : (blockIdx.z == 1) ? C1 : C2;
    gemm2h_core<1024, 16>(A, BT, C, 0);
}

__global__ __launch_bounds__(512, 2) void gemm_out_mfma(const unsigned short* __restrict__ A,
                                                        const unsigned short* __restrict__ BT,
                                                        unsigned short* __restrict__ P0,
                                                        unsigned short* __restrict__ P1,
                                                        unsigned short* __restrict__ P2,
                                                        unsigned short* __restrict__ P3) {
    unsigned short* P = (blockIdx.z == 0) ? P0 : (blockIdx.z == 1) ? P1
                      : (blockIdx.z == 2) ? P2 : P3;
    gemm2h_core<2048, 8>(A, BT, P, blockIdx.z * 512);
}

__global__ __launch_bounds__(256) void out_reduce_kernel(const float* __restrict__ x,
                                                         const unsigned short* __restrict__ P0,
                                                         const unsigned short* __restrict__ P1,
                                                         const unsigned short* __restrict__ P2,
                                                         const unsigned short* __restrict__ P3,
                                                         float* __restrict__ out) {
    int g = blockIdx.x * 256 + threadIdx.x;
    size_t e = (size_t)g * 4;
    float4 xv = *(const float4*)&x[e];
    ushort4 a = *(const ushort4*)&P0[e];
    ushort4 b = *(const ushort4*)&P1[e];
    ushort4 c = *(const ushort4*)&P2[e];
    ushort4 d = *(const ushort4*)&P3[e];
    float4 o;
    o.x = xv.x + bf2f(a.x) + bf2f(b.x) + bf2f(c.x) + bf2f(d.x);
    o.y = xv.y + bf2f(a.y) + bf2f(b.y) + bf2f(c.y) + bf2f(d.y);
    o.z = xv.z + bf2f(a.z) + bf2f(b.z) + bf2f(c.z) + bf2f(d.z);
    o.w = xv.w + bf2f(a.w) + bf2f(b.w) + bf2f(c.w) + bf2f(d.w);
    *(float4*)&out[e] = o;
}

// ---------------------------------------------------------------------------
// Linear attention constants
// ---------------------------------------------------------------------------
#define PHI 160
#define NCH 32
#define KVROWS 65
#define CH_STRIDE ((size_t)32 * KVROWS * PHI)
#define KSTR 72   // staged raw K/Q row stride (conflict-free)
#define FSTR 18   // kf_l/qf_l row stride: 36B = 9 dwords -> 2 lanes/bank (free)

// ---------------------------------------------------------------------------
// FUSED: sliding-window attention (blockIdx.x < 32) + lin_kv (>= 32).
// ---------------------------------------------------------------------------
__global__ __launch_bounds__(256) void win_linkv_kernel(const unsigned short* __restrict__ q_bf,
                                                        const unsigned short* __restrict__ k_bf,
                                                        const float* __restrict__ Wkf,
                                                        const unsigned short* __restrict__ v_bf,
                                                        unsigned short* __restrict__ cat_bf,
                                                        unsigned short* __restrict__ kvbuf) {
    __shared__ __align__(16) unsigned short POOL[21136];   // 42.3 KB
    __shared__ float sclut[136];
    int bh = blockIdx.y;
    int h = bh & 15;
    int b = bh >> 4;
    int tid = threadIdx.x;
    int lane = tid & 63;

    if (blockIdx.x < TT / 64) {
        // =================== WIN path ===================
        unsigned short* Qs = POOL;
        unsigned short* Ks = POOL + 4096;
        unsigned short* Vt = POOL + 12288;
        unsigned short* Pl = POOL;
        int qtile = blockIdx.x;
        int wv = tid >> 6;
        int qr0 = wv * 16;
        int t0 = qtile * 64;
        int k0 = t0 - 64;

        #pragma unroll
        for (int half = 0; half < 2; half++) {
            int slot = tid + half * 256;
            int row = slot >> 3, pos = slot & 7;
            int o = (pos - row) & 7;
            gl2lds16(q_bf + (size_t)(b * TT + t0 + row) * (NH * HD) + h * HD + o * 8,
                     &Qs[slot * 8]);
        }
        #pragma unroll
        for (int qd = 0; qd < 4; qd++) {
            int slot = tid + qd * 256;
            int row = slot >> 3, pos = slot & 7;
            int o = (pos - row) & 7;
            int kg = k0 + row;
            if (kg >= 0) {
                gl2lds16(k_bf + (size_t)(b * TT + kg) * (NH * HD) + h * HD + o * 8,
                         &Ks[slot * 8]);
            } else {
                uint4 z = {0, 0, 0, 0};
                *(uint4*)&Ks[slot * 8] = z;
            }
        }
        {
            int kk = tid & 127;
            int dh = tid >> 7;
            int kg = k0 + kk;
            unsigned short tmp[32];
            if (kg >= 0) {
                size_t base = (size_t)(b * TT + kg) * (NH * HD) + h * HD + dh * 32;
                *(uint4*)&tmp[0]  = *(const uint4*)&v_bf[base];
                *(uint4*)&tmp[8]  = *(const uint4*)&v_bf[base + 8];
                *(uint4*)&tmp[16] = *(const uint4*)&v_bf[base + 16];
                *(uint4*)&tmp[24] = *(const uint4*)&v_bf[base + 24];
            } else {
                #pragma unroll
                for (int d = 0; d < 32; d++) tmp[d] = 0;
            }
            int o = kk >> 3, klow = kk & 7;
            #pragma unroll
            for (int d = 0; d < 32; d++) {
                int dim = dh * 32 + d;
                Vt[dim * 128 + ((o + dim) & 15) * 8 + klow] = tmp[d];
            }
        }
        __syncthreads();

        int hi = lane >> 4;
        int lan15 = lane & 15;
        f32x4 sc[8];
        #pragma unroll
        for (int nt = 0; nt < 8; nt++) sc[nt] = (f32x4){0.f, 0.f, 0.f, 0.f};
        #pragma unroll
        for (int ks = 0; ks < 2; ks++) {
            int m = qr0 + lan15;
            int oA = ks * 4 + hi;
            bf16x8 a = *(const bf16x8*)&Qs[m * 64 + ((oA + m) & 7) * 8];
            #pragma unroll
            for (int nt = 0; nt < 8; nt++) {
                int n = nt * 16 + lan15;
                bf16x8 bb = *(const bf16x8*)&Ks[n * 64 + ((oA + n) & 7) * 8];
                sc[nt] = __builtin_amdgcn_mfma_f32_16x16x32_bf16(a, bb, sc[nt], 0, 0, 0);
            }
        }

        float lrow[4];
        #pragma unroll
        for (int r = 0; r < 4; r++) {
            int tq = t0 + qr0 + hi * 4 + r;
            float mx = -1e30f;
            #pragma unroll
            for (int nt = 0; nt < 8; nt++) {
                int s = k0 + nt * 16 + lan15;
                bool ok = (s >= 0) && (s <= tq) && (s >= tq - WIN);
                float vv = ok ? sc[nt][r] * 0.125f : -1e30f;
                sc[nt][r] = vv;
                mx = fmaxf(mx, vv);
            }
            #pragma unroll
            for (int off = 1; off < 16; off <<= 1) mx = fmaxf(mx, __shfl_xor(mx, off, 64));
            float ls = 0.f;
            #pragma unroll
            for (int nt = 0; nt < 8; nt++) {
                float e = __expf(sc[nt][r] - mx);
                sc[nt][r] = e;
                ls += e;
            }
            #pragma unroll
            for (int off = 1; off < 16; off <<= 1) ls += __shfl_xor(ls, off, 64);
            lrow[r] = ls;
        }

        __syncthreads();   // Qs/Ks reads complete in ALL waves before Pl overwrite

        #pragma unroll
        for (int nt = 0; nt < 8; nt++) {
            #pragma unroll
            for (int r = 0; r < 4; r++) {
                int row = qr0 + hi * 4 + r;
                int col = nt * 16 + lan15;
                Pl[row * 128 + (((col >> 3) + row) & 15) * 8 + (col & 7)] = f2bf(sc[nt][r]);
            }
        }
        __syncthreads();

        f32x4 y[4];
        #pragma unroll
        for (int nt = 0; nt < 4; nt++) y[nt] = (f32x4){0.f, 0.f, 0.f, 0.f};
        #pragma unroll
        for (int ks = 0; ks < 4; ks++) {
            int m = qr0 + lan15;
            int oA = ks * 4 + hi;
            bf16x8 a = *(const bf16x8*)&Pl[m * 128 + ((oA + m) & 15) * 8];
            #pragma unroll
            for (int nt = 0; nt < 4; nt++) {
                int n = nt * 16 + lan15;
                bf16x8 bb = *(const bf16x8*)&Vt[n * 128 + ((oA + n) & 15) * 8];
                y[nt] = __builtin_amdgcn_mfma_f32_16x16x32_bf16(a, bb, y[nt], 0, 0, 0);
            }
        }

        #pragma unroll
        for (int nt = 0; nt < 4; nt++) {
            #pragma unroll
            for (int r = 0; r < 4; r++) {
                int row = qr0 + hi * 4 + r;
                int dim = nt * 16 + lan15;
                cat_bf[(size_t)(b * TT + t0 + row) * (2 * DM) + DM + h * HD + dim] =
                    f2bf(y[nt][r] / lrow[r]);
            }
        }
        return;
    }

    // =================== LIN_KV path ===================
    {
        unsigned short* kf_l = POOL;                 // 64 x FSTR
        unsigned short* PhiT = POOL + 1152;
        unsigned short* Vt   = POOL + 15744;
        unsigned short* iu   = POOL + 20864;
        unsigned short* ju   = POOL + 21000;
        int c = blockIdx.x - TT / 64;
        int w = tid >> 6;
        int hi = lane >> 4, l15 = lane & 15;

        unsigned short* ks_l = &PhiT[0];            // 64xKSTR staged K rows
        float* Wf = (float*)&PhiT[64 * KSTR];       // 64x16 f32 weights

        if (tid < 136) {
            int qq = tid, i = 0;
            while (qq >= 16 - i) { qq -= 16 - i; i++; }
            iu[tid] = (unsigned short)i; ju[tid] = (unsigned short)(i + qq);
            sclut[tid] = (qq == 0) ? 0.5f : 0.70710678118654752f;
        }
        {
            int r = tid >> 2, q16 = (tid & 3) * 16;
            size_t gb = ((size_t)(b * TT + c * 64 + r)) * DM + h * HD + q16;
            *(uint4*)&ks_l[r * KSTR + q16]     = *(const uint4*)&k_bf[gb];
            *(uint4*)&ks_l[r * KSTR + q16 + 8] = *(const uint4*)&k_bf[gb + 8];
        }
        ((float4*)Wf)[tid] = ((const float4*)Wkf)[tid];
        {
            int p = tid & 31, dq = (tid >> 5) * 8;
            size_t base0 = ((size_t)(b * TT + c * 64 + 2 * p)) * DM + h * HD + dq;
            unsigned short a[8], bq[8];
            *(uint4*)a  = *(const uint4*)&v_bf[base0];
            *(uint4*)bq = *(const uint4*)&v_bf[base0 + DM];
            int colo = p >> 2, coll = (2 * p) & 7;
            #pragma unroll
            for (int d = 0; d < 8; d++) {
                int row = dq + d;
                ushort2 u; u.x = a[d]; u.y = bq[d];
                *(ushort2*)&Vt[row * 64 + ((colo + row) & 7) * 8 + coll] = u;
            }
            #pragma unroll
            for (int i = 0; i < 4; i++) {
                int e = tid + i * 256;
                Vt[(64 + (e >> 6)) * 64 + (e & 63)] = 0x3F80;
            }
        }
        __syncthreads();
        {
            int r = tid >> 2, f0 = (tid & 3) * 4;
            const unsigned short* kr = &ks_l[r * KSTR];
            float a0 = 0.f, a1 = 0.f, a2 = 0.f, a3 = 0.f;
            #pragma unroll 8
            for (int d = 0; d < HD; d++) {
                float kv = bf2f(kr[d]);
                const float* wr = &Wf[d * FEAT + f0];
                a0 += kv * wr[0]; a1 += kv * wr[1]; a2 += kv * wr[2]; a3 += kv * wr[3];
            }
            ushort2 o01; o01.x = f2bf(a0); o01.y = f2bf(a1);
            ushort2 o23; o23.x = f2bf(a2); o23.y = f2bf(a3);
            *(ushort2*)&kf_l[r * FSTR + f0]     = o01;
            *(ushort2*)&kf_l[r * FSTR + f0 + 2] = o23;
        }
        __syncthreads();
        {
            int s = tid & 63, fb = tid >> 6;
            const unsigned short* krow = &kf_l[s * FSTR];
            for (int it = 0; it < 40; it++) {
                int f = fb * 40 + it;
                float val;
                if (f == 0) val = 1.f;
                else if (f < 17) val = bf2f(krow[f - 1]);
                else if (f < 153) { int qq = f - 17; val = bf2f(krow[iu[qq]]) * bf2f(krow[ju[qq]]) * sclut[qq]; }
                else val = 0.f;   // f in [153,160): zero padding (guard load-bearing!)
                PhiT[f * 76 + s] = f2bf(val);
            }
        }
        __syncthreads();
        f32x4 acc[5][3];
        #pragma unroll
        for (int m = 0; m < 5; m++)
            #pragma unroll
            for (int j = 0; j < 3; j++) acc[m][j] = (f32x4){0.f, 0.f, 0.f, 0.f};
        #pragma unroll
        for (int ks = 0; ks < 2; ks++) {
            bf16x8 bfrag[3];
            #pragma unroll
            for (int j = 0; j < 3; j++)
                bfrag[j] = *(const bf16x8*)&PhiT[((3 * w + j) * 16 + l15) * 76 + ks * 32 + hi * 8];
            #pragma unroll
            for (int m = 0; m < 5; m++) {
                int mrow = m * 16 + l15;
                bf16x8 afrag = *(const bf16x8*)&Vt[mrow * 64 + (((ks * 4 + hi) + mrow) & 7) * 8];
                #pragma unroll
                for (int j = 0; j < 3; j++)
                    acc[m][j] = __builtin_amdgcn_mfma_f32_16x16x32_bf16(afrag, bfrag[j], acc[m][j], 0, 0, 0);
            }
        }
        size_t obase = ((size_t)c * 32 + bh) * (KVROWS * PHI);
        #pragma unroll
        for (int m = 0; m < 5; m++) {
            #pragma unroll
            for (int j = 0; j < 3; j++) {
                int f = (3 * w + j) * 16 + l15;
                if (f >= PHI) continue;
                #pragma unroll
                for (int r = 0; r < 4; r++) {
                    int row = m * 16 + hi * 4 + r;
                    if (row >= KVROWS) continue;
                    kvbuf[obase + row * PHI + f] = f2bf(acc[m][j][r]);
                }
            }
        }
    }
}

// Phase C: in-place exclusive prefix over chunks. grid (41, 32 bh)
__global__ __launch_bounds__(256) void lin_scan_kernel(unsigned short* __restrict__ kvbuf) {
    int e = blockIdx.x * 256 + threadIdx.x;
    int bh = blockIdx.y;
    if (e >= KVROWS * PHI) return;
    float acc = 0.f;
    size_t off = (size_t)bh * (KVROWS * PHI) + e;
    for (int c = 0; c < NCH; c++) {
        float vv = bf2f(kvbuf[off]);
        kvbuf[off] = f2bf(acc);
        acc += vv;
        off += CH_STRIDE;
    }
}

// Phase D: outputs. grid (32 chunks, 32 bh), 256 threads (R14 form).
__global__ __launch_bounds__(256) void lin_out_kernel(const unsigned short* __restrict__ q_bf,
                                                      const unsigned short* __restrict__ k_bf,
                                                      const float* __restrict__ Wqf,
                                                      const float* __restrict__ Wkf,
                                                      const unsigned short* __restrict__ v_bf,
                                                      const unsigned short* __restrict__ kvbuf,
                                                      unsigned short* __restrict__ cat_bf) {
    int c = blockIdx.x, bh = blockIdx.y;
    int h = bh & 15, b = bh >> 4;
    int tid = threadIdx.x, lane = tid & 63, w = tid >> 6;
    int hi = lane >> 4, l15 = lane & 15;

    __shared__ unsigned short qf_l[64 * FSTR];
    __shared__ __align__(16) unsigned short kf_lb[64 * 34];   // cols 16..31 zero
    __shared__ __align__(16) unsigned short KVS_l[80 * 164];  // rows 65..79 zero
    __shared__ __align__(16) unsigned short Vt[80 * 64];      // swizzled + ones rows
    __shared__ __align__(16) unsigned short Phi_l[64 * 164];  // [token][f]
    __shared__ __align__(16) unsigned short P_l[64 * 64];     // swizzled
    __shared__ unsigned short iu[136], ju[136];
    __shared__ float sclut[136];

    unsigned short* qs_l = &KVS_l[0];              // 64xKSTR staged Q rows
    unsigned short* ks_l = &KVS_l[64 * KSTR];      // 64xKSTR staged K rows
    float* Wq_s = (float*)&Phi_l[0];               // 4KB
    float* Wk_s = (float*)&Phi_l[2048];            // 4KB

    if (tid < 136) {
        int qq = tid, i = 0;
        while (qq >= 16 - i) { qq -= 16 - i; i++; }
        iu[tid] = (unsigned short)i; ju[tid] = (unsigned short)(i + qq);
        sclut[tid] = (qq == 0) ? 0.5f : 0.70710678118654752f;
    }
    {   // stage Q and K rows coalesced (stride KSTR)
        int r = tid >> 2, q16 = (tid & 3) * 16;
        size_t gq = ((size_t)(b * TT + c * 64 + r)) * DM + h * HD + q16;
        *(uint4*)&qs_l[r * KSTR + q16]     = *(const uint4*)&q_bf[gq];
        *(uint4*)&qs_l[r * KSTR + q16 + 8] = *(const uint4*)&q_bf[gq + 8];
        *(uint4*)&ks_l[r * KSTR + q16]     = *(const uint4*)&k_bf[gq];
        *(uint4*)&ks_l[r * KSTR + q16 + 8] = *(const uint4*)&k_bf[gq + 8];
    }
    ((float4*)Wq_s)[tid] = ((const float4*)Wqf)[tid];
    ((float4*)Wk_s)[tid] = ((const float4*)Wkf)[tid];
    {   // stage V^T swizzled + ones rows
        int p = tid & 31, dq = (tid >> 5) * 8;
        size_t base0 = ((size_t)(b * TT + c * 64 + 2 * p)) * DM + h * HD + dq;
        unsigned short a[8], bq[8];
        *(uint4*)a  = *(const uint4*)&v_bf[base0];
        *(uint4*)bq = *(const uint4*)&v_bf[base0 + DM];
        int colo = p >> 2, coll = (2 * p) & 7;
        #pragma unroll
        for (int d = 0; d < 8; d++) {
            int row = dq + d;
            ushort2 u; u.x = a[d]; u.y = bq[d];
            *(ushort2*)&Vt[row * 64 + ((colo + row) & 7) * 8 + coll] = u;
        }
        #pragma unroll
        for (int i = 0; i < 4; i++) {
            int e = tid + i * 256;
            Vt[(64 + (e >> 6)) * 64 + (e & 63)] = 0x3F80;
        }
    }
    __syncthreads();
    {   // compute qf_l and kf_lb (fp32, d ascending)
        int r = tid >> 2, f0 = (tid & 3) * 4;
        const unsigned short* qr = &qs_l[r * KSTR];
        const unsigned short* kr = &ks_l[r * KSTR];
        float qa0=0.f,qa1=0.f,qa2=0.f,qa3=0.f, ka0=0.f,ka1=0.f,ka2=0.f,ka3=0.f;
        #pragma unroll 8
        for (int d = 0; d < HD; d++) {
            float qv = bf2f(qr[d]);
            float kv = bf2f(kr[d]);
            const float* wq = &Wq_s[d * FEAT + f0];
            const float* wk = &Wk_s[d * FEAT + f0];
            qa0 += qv * wq[0]; qa1 += qv * wq[1]; qa2 += qv * wq[2]; qa3 += qv * wq[3];
            ka0 += kv * wk[0]; ka1 += kv * wk[1]; ka2 += kv * wk[2]; ka3 += kv * wk[3];
        }
        ushort2 q01; q01.x = f2bf(qa0); q01.y = f2bf(qa1);
        ushort2 q23; q23.x = f2bf(qa2); q23.y = f2bf(qa3);
        *(ushort2*)&qf_l[r * FSTR + f0]     = q01;
        *(ushort2*)&qf_l[r * FSTR + f0 + 2] = q23;
        ushort4 ok; ok.x = f2bf(ka0); ok.y = f2bf(ka1); ok.z = f2bf(ka2); ok.w = f2bf(ka3);
        *(ushort4*)&kf_lb[r * 34 + f0] = ok;
        ushort4 z4 = {0, 0, 0, 0};
        *(ushort4*)&kf_lb[r * 34 + 16 + f0] = z4;
    }
    __syncthreads();
    {   // stage KVS rows 0..64 (overwrites qs/ks scratch - post-sync)
        size_t gbase = ((size_t)c * 32 + bh) * (KVROWS * PHI);
        #pragma unroll
        for (int i = 0; i < 11; i++) {
            int e4 = tid + i * 256;
            if (e4 < KVROWS * 40) {
                int r = e4 / 40, q4 = (e4 % 40) * 4;
                *(ushort4*)&KVS_l[r * 164 + q4] =
                    *(const ushort4*)&kvbuf[gbase + r * PHI + q4];
            }
        }
        #pragma unroll
        for (int i = 0; i < 3; i++) {
            int e4 = tid + i * 256;
            if (e4 < 15 * 40) {
                int r = 65 + e4 / 40, q4 = (e4 % 40) * 4;
                ushort4 z4 = {0, 0, 0, 0};
                *(ushort4*)&KVS_l[r * 164 + q4] = z4;
            }
        }
    }
    {   // build Phi_l[token][f] (overwrites Wq_s/Wk_s scratch - post-sync)
        int s = tid & 63, fb = tid >> 6;
        const unsigned short* qrow = &qf_l[s * FSTR];
        for (int it = 0; it < 40; it++) {
            int f = fb * 40 + it;
            float val;
            if (f == 0) val = 1.f;
            else if (f < 17) val = bf2f(qrow[f - 1]);
            else if (f < 153) { int qq = f - 17; val = bf2f(qrow[iu[qq]]) * bf2f(qrow[ju[qq]]) * sclut[qq]; }
            else val = 0.f;   // f in [153,160): zero padding (guard load-bearing!)
            Phi_l[s * 164 + f] = f2bf(val);
        }
    }
    __syncthreads();

    f32x4 acc[5];
    #pragma unroll
    for (int n = 0; n < 5; n++) acc[n] = (f32x4){0.f, 0.f, 0.f, 0.f};

    int t_m = w * 16 + l15;

    // GEMM1: Phi (LDS) x KVS
    #pragma unroll
    for (int ks = 0; ks < 5; ks++) {
        bf16x8 af = *(const bf16x8*)&Phi_l[t_m * 164 + ks * 32 + hi * 8];
        #pragma unroll
        for (int n = 0; n < 5; n++) {
            bf16x8 bb = *(const bf16x8*)&KVS_l[(n * 16 + l15) * 164 + ks * 32 + hi * 8];
            acc[n] = __builtin_amdgcn_mfma_f32_16x16x32_bf16(af, bb, acc[n], 0, 0, 0);
        }
    }

    // intra-chunk scores: S = (1 + qf.kf/2)^2, causal (diag included)
    {
        union { unsigned short u[8]; bf16x8 v; } aq;
        #pragma unroll
        for (int j = 0; j < 8; j++) {
            int f = hi * 8 + j;
            aq.u[j] = (f < 16) ? qf_l[t_m * FSTR + f] : (unsigned short)0;
        }
        #pragma unroll
        for (int n = 0; n < 4; n++) {
            bf16x8 bk = *(const bf16x8*)&kf_lb[(n * 16 + l15) * 34 + hi * 8];
            f32x4 zv = {0.f, 0.f, 0.f, 0.f};
            f32x4 sc = __builtin_amdgcn_mfma_f32_16x16x32_bf16(aq.v, bk, zv, 0, 0, 0);
            int sl = n * 16 + l15;
            #pragma unroll
            for (int r = 0; r < 4; r++) {
                int rl = w * 16 + hi * 4 + r;
                float sv = 1.f + 0.5f * sc[r];
                sv = sv * sv;
                if (sl > rl) sv = 0.f;
                P_l[rl * 64 + (((sl >> 3) + rl) & 7) * 8 + (sl & 7)] = f2bf(sv);
            }
        }
    }
    __syncthreads();

    // GEMM2: P x Vt (y into cols 0..63, z into col 64 via ones rows)
    #pragma unroll
    for (int ks = 0; ks < 2; ks++) {
        int oA = ks * 4 + hi;
        bf16x8 a = *(const bf16x8*)&P_l[t_m * 64 + ((oA + t_m) & 7) * 8];
        #pragma unroll
        for (int n = 0; n < 5; n++) {
            int nrow = n * 16 + l15;
            bf16x8 bb = *(const bf16x8*)&Vt[nrow * 64 + ((oA + nrow) & 7) * 8];
            acc[n] = __builtin_amdgcn_mfma_f32_16x16x32_bf16(a, bb, acc[n], 0, 0, 0);
        }
    }

    // epilogue: z lives in col 64 (l15==0 of acc[4]); broadcast per row
    #pragma unroll
    for (int r = 0; r < 4; r++) {
        float zz = __shfl(acc[4][r], (lane & 48), 64);
        int token = c * 64 + w * 16 + hi * 4 + r;
        #pragma unroll
        for (int n = 0; n < 4; n++) {
            int d = n * 16 + l15;
            cat_bf[((size_t)(b * TT + token)) * (2 * DM) + h * HD + d] =
                f2bf(acc[n][r] / (zz + 1e-6f));
        }
    }
}

// ---------------------------------------------------------------------------
extern "C" void kernel_launch(void* const* d_in, const int* in_sizes, int n_in,
                              void* d_out, int out_size, void* d_ws, size_t ws_size,
                              hipStream_t stream) {
    const float* x      = (const float*)d_in[0];
    const float* norm_w = (const float*)d_in[1];
    const float* Wq     = (const float*)d_in[2];
    const float* Wk     = (const float*)d_in[3];
    const float* Wv     = (const float*)d_in[4];
    const float* Wqf    = (const float*)d_in[5];
    const float* Wkf    = (const float*)d_in[6];
    const float* Wout   = (const float*)d_in[7];
    float* out = (float*)d_out;

    char* p = (char*)d_ws;
    unsigned short* h_bf = (unsigned short*)p; p += (size_t)RTOT * DM * 2;       // 8 MB
    unsigned short* WqT  = (unsigned short*)p; p += (size_t)DM * DM * 2;         // 2 MB
    unsigned short* WkT  = (unsigned short*)p; p += (size_t)DM * DM * 2;
    unsigned short* WvT  = (unsigned short*)p; p += (size_t)DM * DM * 2;
    unsigned short* WoT  = (unsigned short*)p; p += (size_t)DM * 2 * DM * 2;     // 4 MB
    unsigned short* q_bf = (unsigned short*)p; p += (size_t)RTOT * DM * 2;       // 8 MB
    unsigned short* k_bf = (unsigned short*)p; p += (size_t)RTOT * DM * 2;
    unsigned short* v_bf = (unsigned short*)p; p += (size_t)RTOT * DM * 2;
    p += (size_t)RTOT * NH * FEAT * 2 * 2;   // (former qf/kf buffers - unused)
    unsigned short* cat_bf = (unsigned short*)p; p += (size_t)RTOT * 2 * DM * 2;   // 16 MB
    unsigned short* kvbuf  = (unsigned short*)p; p += (size_t)NCH * 32 * KVROWS * PHI * 2; // 21.3 MB
    unsigned short* P0 = (unsigned short*)p; p += (size_t)RTOT * DM * 2;           // 8 MB
    unsigned short* P1 = (unsigned short*)p; p += (size_t)RTOT * DM * 2;           // 8 MB
    unsigned short* P2 = h_bf;
    unsigned short* P3 = q_bf;

    prep_kernel<<<RTOT + 1280, 256, 0, stream>>>(x, norm_w, h_bf,
                                                 Wq, Wk, Wv, Wout, WqT, WkT, WvT, WoT);
    gemm_qkv_mfma<<<dim3(4, 16, 3), 512, 0, stream>>>(h_bf, WqT, WkT, WvT, q_bf, k_bf, v_bf);
    win_linkv_kernel<<<dim3(2 * (TT / 64), BB * NH), 256, 0, stream>>>(q_bf, k_bf, Wkf, v_bf, cat_bf, kvbuf);
    lin_scan_kernel<<<dim3((KVROWS * PHI + 255) / 256, BB * NH), 256, 0, stream>>>(kvbuf);
    lin_out_kernel<<<dim3(NCH, BB * NH), 256, 0, stream>>>(q_bf, k_bf, Wqf, Wkf, v_bf, kvbuf, cat_bf);
    gemm_out_mfma<<<dim3(4, 16, 4), 512, 0, stream>>>(cat_bf, WoT, P0, P1, P2, P3);
    out_reduce_kernel<<<RTOT * DM / 1024, 256, 0, stream>>>(x, P0, P1, P2, P3, out);
}